// Round 18
// baseline (473.759 us; speedup 1.0000x reference)
//
#include <hip/hip_runtime.h>
#include <hip/hip_bf16.h>
#include <cstddef>
#include <cstdint>

#define Bb 2
#define Tt 1024
#define Hh 2048
#define NHh 8
#define Dd 128
#define Pp (NHh * Dd)   // 1024
#define Kk 4
#define EPSf 1e-6f
#define SCALEf 0.08838834764831845f  // D^-0.5
#define DVQ 16          // dv-splits per (b,h): 16 blocks x 8 columns
#define CHUNK 8         // timesteps per barrier round in scan

typedef short bf16x8 __attribute__((ext_vector_type(8)));
typedef float f32x4 __attribute__((ext_vector_type(4)));
typedef float f32x2 __attribute__((ext_vector_type(2)));   // -> v_pk_*_f32

// DPP rotate-add: 16-lane row sum in 4 VALU ops (all lanes get the sum).
template <int CTRL>
__device__ __forceinline__ float dpp_add(float x) {
  int yi = __builtin_amdgcn_update_dpp(0, __builtin_bit_cast(int, x), CTRL, 0xF, 0xF, true);
  return x + __builtin_bit_cast(float, yi);
}
__device__ __forceinline__ float row16_sum(float x) {
  x = dpp_add<0xB1>(x);
  x = dpp_add<0x4E>(x);
  x = dpp_add<0x124>(x);
  x = dpp_add<0x128>(x);
  return x;
}

// async global->LDS; lds base must be wave-uniform (HW adds lane*size).
__device__ __forceinline__ void gload_lds16(const void* g, void* l) {
  __builtin_amdgcn_global_load_lds((const __attribute__((address_space(1))) void*)g,
                                   (__attribute__((address_space(3))) void*)l, 16, 0, 0);
}
__device__ __forceinline__ void gload_lds4(const void* g, void* l) {
  __builtin_amdgcn_global_load_lds((const __attribute__((address_space(1))) void*)g,
                                   (__attribute__((address_space(3))) void*)l, 4, 0, 0);
}

// ---------------- f32 -> bf16 convert (8 elems/thread) ----------------
__global__ __launch_bounds__(256) void cvt_bf16(const float* __restrict__ src,
                                                __hip_bfloat16* __restrict__ dst, int n) {
  const int i = (blockIdx.x * 256 + threadIdx.x) * 8;
  if (i >= n) return;
  const float4 a = *reinterpret_cast<const float4*>(src + i);
  const float4 b = *reinterpret_cast<const float4*>(src + i + 4);
  __hip_bfloat16 t[8];
  t[0] = __float2bfloat16(a.x); t[1] = __float2bfloat16(a.y);
  t[2] = __float2bfloat16(a.z); t[3] = __float2bfloat16(a.w);
  t[4] = __float2bfloat16(b.x); t[5] = __float2bfloat16(b.y);
  t[6] = __float2bfloat16(b.z); t[7] = __float2bfloat16(b.w);
  *reinterpret_cast<uint4*>(dst + i) = *reinterpret_cast<const uint4*>(t);
}

// ---------------- 4-array f32 -> bf16 (fused weight conversion) ----------------
__global__ __launch_bounds__(256) void cvt_bf16_x4(const float* __restrict__ s0,
                                                   const float* __restrict__ s1,
                                                   const float* __restrict__ s2,
                                                   const float* __restrict__ s3,
                                                   __hip_bfloat16* __restrict__ d0,
                                                   __hip_bfloat16* __restrict__ d1,
                                                   __hip_bfloat16* __restrict__ d2,
                                                   __hip_bfloat16* __restrict__ d3,
                                                   int nper) {
  const int bpa = nper / 2048;
  const int a = blockIdx.x / bpa;
  const int i = (blockIdx.x % bpa) * 2048 + threadIdx.x * 8;
  const float* src = (a == 0) ? s0 : (a == 1) ? s1 : (a == 2) ? s2 : s3;
  __hip_bfloat16* dst = (a == 0) ? d0 : (a == 1) ? d1 : (a == 2) ? d2 : d3;
  const float4 x = *reinterpret_cast<const float4*>(src + i);
  const float4 y = *reinterpret_cast<const float4*>(src + i + 4);
  __hip_bfloat16 t[8];
  t[0] = __float2bfloat16(x.x); t[1] = __float2bfloat16(x.y);
  t[2] = __float2bfloat16(x.z); t[3] = __float2bfloat16(x.w);
  t[4] = __float2bfloat16(y.x); t[5] = __float2bfloat16(y.y);
  t[6] = __float2bfloat16(y.z); t[7] = __float2bfloat16(y.w);
  *reinterpret_cast<uint4*>(dst + i) = *reinterpret_cast<const uint4*>(t);
}

// ---------------- f32 -> (hi, lo) bf16 split ----------------
__global__ __launch_bounds__(256) void cvt_split(const float* __restrict__ src,
                                                 __hip_bfloat16* __restrict__ hi,
                                                 __hip_bfloat16* __restrict__ lo, int n) {
  const int i = (blockIdx.x * 256 + threadIdx.x) * 8;
  if (i >= n) return;
  __hip_bfloat16 th[8], tl[8];
#pragma unroll
  for (int j = 0; j < 2; j++) {
    const float4 a = *reinterpret_cast<const float4*>(src + i + j * 4);
    const float f[4] = {a.x, a.y, a.z, a.w};
#pragma unroll
    for (int e = 0; e < 4; e++) {
      const __hip_bfloat16 h = __float2bfloat16(f[e]);
      th[j * 4 + e] = h;
      tl[j * 4 + e] = __float2bfloat16(f[e] - __bfloat162float(h));
    }
  }
  *reinterpret_cast<uint4*>(hi + i) = *reinterpret_cast<const uint4*>(th);
  *reinterpret_cast<uint4*>(lo + i) = *reinterpret_cast<const uint4*>(tl);
}

// ---- NN f32 GEMM with bf16(-split) output: C[M,N] = A[M,K] @ B[K,N] ----
__global__ __launch_bounds__(256) void gemm_nn_split(const float* __restrict__ A,
                                                     const float* __restrict__ B,
                                                     __hip_bfloat16* __restrict__ Chi,
                                                     __hip_bfloat16* __restrict__ Clo,
                                                     int M, int N, int K, int mode) {
  __shared__ float As[64][33];
  __shared__ float Bs[32][65];
  const int bm = blockIdx.y * 64, bn = blockIdx.x * 64;
  const int tid = threadIdx.x;
  const int tx = tid & 15, ty = tid >> 4;
  float acc[4][4];
#pragma unroll
  for (int i = 0; i < 4; i++)
#pragma unroll
    for (int j = 0; j < 4; j++) acc[i][j] = 0.f;
  for (int k0 = 0; k0 < K; k0 += 32) {
#pragma unroll
    for (int i = 0; i < 8; i++) {
      const int idx = tid + i * 256;
      const int r = idx >> 5, c = idx & 31;
      As[r][c] = A[(size_t)(bm + r) * K + k0 + c];
    }
#pragma unroll
    for (int i = 0; i < 8; i++) {
      const int idx = tid + i * 256;
      const int r = idx >> 6, c = idx & 63;
      Bs[r][c] = B[(size_t)(k0 + r) * N + bn + c];
    }
    __syncthreads();
#pragma unroll
    for (int kk = 0; kk < 32; kk++) {
      float a[4], b[4];
#pragma unroll
      for (int i = 0; i < 4; i++) a[i] = As[ty * 4 + i][kk];
#pragma unroll
      for (int j = 0; j < 4; j++) b[j] = Bs[kk][tx * 4 + j];
#pragma unroll
      for (int i = 0; i < 4; i++)
#pragma unroll
        for (int j = 0; j < 4; j++) acc[i][j] += a[i] * b[j];
    }
    __syncthreads();
  }
#pragma unroll
  for (int i = 0; i < 4; i++) {
    const int row = bm + ty * 4 + i;
#pragma unroll
    for (int j = 0; j < 4; j++) {
      const int col = bn + tx * 4 + j;
      const float v = acc[i][j];
      const __hip_bfloat16 h = __float2bfloat16(v);
      Chi[(size_t)row * N + col] = h;
      if (mode == 0) Clo[(size_t)row * N + col] = __float2bfloat16(v - __bfloat162float(h));
    }
  }
}

// ------ bf16 MFMA NT GEMM via global_load_lds (m97 structure): 128x128, BK=64 ------
__global__ __launch_bounds__(256) void gemm_bf16_lds(const __hip_bfloat16* __restrict__ A,
                                                     const __hip_bfloat16* __restrict__ B,
                                                     float* __restrict__ C,
                                                     __hip_bfloat16* __restrict__ Cbf,
                                                     int M, int N, int K, int outmode) {
  __shared__ __align__(16) __hip_bfloat16 As[128 * 64];
  __shared__ __align__(16) __hip_bfloat16 Bs[128 * 64];
  const int tid = threadIdx.x;
  const int wave = tid >> 6;
  const int lane = tid & 63;
  const int wm = (wave >> 1) * 64;
  const int wn = (wave & 1) * 64;
  const int bm = blockIdx.y * 128;
  const int bn = blockIdx.x * 128;
  const int l15 = lane & 15;
  const int l4 = lane >> 4;
  const int srow = lane >> 3;
  const int scol = (lane & 7) * 8;

  f32x4 acc[4][4];
#pragma unroll
  for (int i = 0; i < 4; i++)
#pragma unroll
    for (int j = 0; j < 4; j++) acc[i][j] = (f32x4){0.f, 0.f, 0.f, 0.f};

  for (int k0 = 0; k0 < K; k0 += 64) {
#pragma unroll
    for (int i = 0; i < 4; i++) {
      const int s = wave * 4 + i;
      const int row = s * 8 + srow;
      gload_lds16(A + (size_t)(bm + row) * K + k0 + scol, &As[s * 512]);
      gload_lds16(B + (size_t)(bn + row) * K + k0 + scol, &Bs[s * 512]);
    }
    __syncthreads();
    bf16x8 af[4][2], bfv[4][2];
#pragma unroll
    for (int kf = 0; kf < 2; kf++) {
      const int kc = kf * 32 + l4 * 8;
#pragma unroll
      for (int mf = 0; mf < 4; mf++)
        af[mf][kf] = *reinterpret_cast<const bf16x8*>(&As[(wm + mf * 16 + l15) * 64 + kc]);
#pragma unroll
      for (int nf = 0; nf < 4; nf++)
        bfv[nf][kf] = *reinterpret_cast<const bf16x8*>(&Bs[(wn + nf * 16 + l15) * 64 + kc]);
    }
#pragma unroll
    for (int kf = 0; kf < 2; kf++)
#pragma unroll
      for (int mf = 0; mf < 4; mf++)
#pragma unroll
        for (int nf = 0; nf < 4; nf++)
          acc[mf][nf] = __builtin_amdgcn_mfma_f32_16x16x32_bf16(af[mf][kf], bfv[nf][kf],
                                                                acc[mf][nf], 0, 0, 0);
    __syncthreads();
  }
#pragma unroll
  for (int mf = 0; mf < 4; mf++) {
#pragma unroll
    for (int nf = 0; nf < 4; nf++) {
      const int col = bn + wn + nf * 16 + l15;
#pragma unroll
      for (int r = 0; r < 4; r++) {
        const int row = bm + wm + mf * 16 + l4 * 4 + r;
        if (outmode == 0) C[(size_t)row * N + col] = acc[mf][nf][r];
        else Cbf[(size_t)row * N + col] = __float2bfloat16(acc[mf][nf][r]);
      }
    }
  }
}

// -- 3-term split-bf16 MFMA NT GEMM via global_load_lds: C = AhBh + AhBl + AlBh --
__global__ __launch_bounds__(256) void gemm_bf16_3t_lds(const __hip_bfloat16* __restrict__ Ahi,
                                                        const __hip_bfloat16* __restrict__ Alo,
                                                        const __hip_bfloat16* __restrict__ Bhi,
                                                        const __hip_bfloat16* __restrict__ Blo,
                                                        float* __restrict__ C,
                                                        int M, int N, int K,
                                                        const float* __restrict__ dtb,
                                                        const float* __restrict__ A_log,
                                                        int gmode) {
  __shared__ __align__(16) __hip_bfloat16 Ahs[64 * 64];
  __shared__ __align__(16) __hip_bfloat16 Als[64 * 64];
  __shared__ __align__(16) __hip_bfloat16 Bhs[128 * 64];
  __shared__ __align__(16) __hip_bfloat16 Bls[128 * 64];
  const int tid = threadIdx.x;
  const int wave = tid >> 6;
  const int lane = tid & 63;
  const int wm = (wave >> 1) * 32;
  const int wn = (wave & 1) * 64;
  const int bm = blockIdx.y * 64;
  const int bn = blockIdx.x * 128;
  const int l15 = lane & 15;
  const int l4 = lane >> 4;
  const int srow = lane >> 3;
  const int scol = (lane & 7) * 8;

  f32x4 acc[2][4];
#pragma unroll
  for (int i = 0; i < 2; i++)
#pragma unroll
    for (int j = 0; j < 4; j++) acc[i][j] = (f32x4){0.f, 0.f, 0.f, 0.f};

  for (int k0 = 0; k0 < K; k0 += 64) {
#pragma unroll
    for (int i = 0; i < 12; i++) {
      const int sid = wave * 12 + i;
      if (sid < 8) {
        const int row = sid * 8 + srow;
        gload_lds16(Ahi + (size_t)(bm + row) * K + k0 + scol, &Ahs[sid * 512]);
      } else if (sid < 16) {
        const int row = (sid - 8) * 8 + srow;
        gload_lds16(Alo + (size_t)(bm + row) * K + k0 + scol, &Als[(sid - 8) * 512]);
      } else if (sid < 32) {
        const int row = (sid - 16) * 8 + srow;
        gload_lds16(Bhi + (size_t)(bn + row) * K + k0 + scol, &Bhs[(sid - 16) * 512]);
      } else {
        const int row = (sid - 32) * 8 + srow;
        gload_lds16(Blo + (size_t)(bn + row) * K + k0 + scol, &Bls[(sid - 32) * 512]);
      }
    }
    __syncthreads();
#pragma unroll
    for (int kf = 0; kf < 2; kf++) {
      const int kc = kf * 32 + l4 * 8;
      bf16x8 ah[2], al[2], bh[4], bl[4];
#pragma unroll
      for (int mf = 0; mf < 2; mf++) {
        ah[mf] = *reinterpret_cast<const bf16x8*>(&Ahs[(wm + mf * 16 + l15) * 64 + kc]);
        al[mf] = *reinterpret_cast<const bf16x8*>(&Als[(wm + mf * 16 + l15) * 64 + kc]);
      }
#pragma unroll
      for (int nf = 0; nf < 4; nf++) {
        bh[nf] = *reinterpret_cast<const bf16x8*>(&Bhs[(wn + nf * 16 + l15) * 64 + kc]);
        bl[nf] = *reinterpret_cast<const bf16x8*>(&Bls[(wn + nf * 16 + l15) * 64 + kc]);
      }
#pragma unroll
      for (int mf = 0; mf < 2; mf++)
#pragma unroll
        for (int nf = 0; nf < 4; nf++) {
          acc[mf][nf] = __builtin_amdgcn_mfma_f32_16x16x32_bf16(ah[mf], bh[nf], acc[mf][nf], 0, 0, 0);
          acc[mf][nf] = __builtin_amdgcn_mfma_f32_16x16x32_bf16(ah[mf], bl[nf], acc[mf][nf], 0, 0, 0);
          acc[mf][nf] = __builtin_amdgcn_mfma_f32_16x16x32_bf16(al[mf], bh[nf], acc[mf][nf], 0, 0, 0);
        }
    }
    __syncthreads();
  }
#pragma unroll
  for (int mf = 0; mf < 2; mf++)
#pragma unroll
    for (int nf = 0; nf < 4; nf++) {
      const int col = bn + wn + nf * 16 + l15;
#pragma unroll
      for (int r = 0; r < 4; r++) {
        const int row = bm + wm + mf * 16 + l4 * 4 + r;
        float val = acc[mf][nf][r];
        if (gmode) {
          const float xv = val + dtb[col];
          const float sp = (xv > 20.f) ? xv : log1pf(expf(xv));
          val = expf(-expf(A_log[col >> 7]) * sp);
        }
        C[(size_t)row * N + col] = val;
      }
    }
}

// ---------------- generic f32 GEMM (fallback only) ----------------
__global__ __launch_bounds__(256) void gemm_nt(const float* __restrict__ A,
                                               const float* __restrict__ Bm,
                                               float* __restrict__ C,
                                               int M, int N, int Kd) {
  __shared__ float As[16][64];
  __shared__ float Bs[16][64];
  const int bm = blockIdx.y * 64;
  const int bn = blockIdx.x * 64;
  const int tid = threadIdx.x;
  const int tx = tid & 15;
  const int ty = tid >> 4;
  const int lr = tid >> 2;
  const int lc = (tid & 3) << 2;
  float acc[4][4];
#pragma unroll
  for (int i = 0; i < 4; i++)
#pragma unroll
    for (int j = 0; j < 4; j++) acc[i][j] = 0.f;
  for (int k0 = 0; k0 < Kd; k0 += 16) {
    float4 a4 = make_float4(0.f, 0.f, 0.f, 0.f);
    float4 b4 = make_float4(0.f, 0.f, 0.f, 0.f);
    const int ar = bm + lr;
    if (ar < M) a4 = *reinterpret_cast<const float4*>(A + (size_t)ar * Kd + k0 + lc);
    const int br = bn + lr;
    if (br < N) b4 = *reinterpret_cast<const float4*>(Bm + (size_t)br * Kd + k0 + lc);
    As[lc + 0][lr] = a4.x; As[lc + 1][lr] = a4.y; As[lc + 2][lr] = a4.z; As[lc + 3][lr] = a4.w;
    Bs[lc + 0][lr] = b4.x; Bs[lc + 1][lr] = b4.y; Bs[lc + 2][lr] = b4.z; Bs[lc + 3][lr] = b4.w;
    __syncthreads();
#pragma unroll
    for (int kk = 0; kk < 16; kk++) {
      float4 av = *reinterpret_cast<const float4*>(&As[kk][ty << 2]);
      float4 bv = *reinterpret_cast<const float4*>(&Bs[kk][tx << 2]);
      float a[4] = {av.x, av.y, av.z, av.w};
      float b[4] = {bv.x, bv.y, bv.z, bv.w};
#pragma unroll
      for (int i = 0; i < 4; i++)
#pragma unroll
        for (int j = 0; j < 4; j++) acc[i][j] += a[i] * b[j];
    }
    __syncthreads();
  }
#pragma unroll
  for (int i = 0; i < 4; i++) {
    const int row = bm + (ty << 2) + i;
    if (row >= M) continue;
#pragma unroll
    for (int j = 0; j < 4; j++) {
      const int col = bn + (tx << 2) + j;
      if (col < N) C[(size_t)row * N + col] = acc[i][j];
    }
  }
}

// ---------------- beta = sigmoid(x @ Wb^T), Wb (NH,H) ----------------
__global__ __launch_bounds__(256) void beta_kernel(const float* __restrict__ x,
                                                   const float* __restrict__ Wb,
                                                   float* __restrict__ beta) {
  __shared__ float xs[Hh];
  const int m = blockIdx.x;
  const int tid = threadIdx.x;
  for (int i = tid; i < Hh; i += 256) xs[i] = x[(size_t)m * Hh + i];
  __syncthreads();
  const int h = tid >> 5;
  const int lane = tid & 31;
  float acc = 0.f;
  for (int i = lane; i < Hh; i += 32) acc += xs[i] * Wb[(size_t)h * Hh + i];
#pragma unroll
  for (int o = 16; o > 0; o >>= 1) acc += __shfl_down(acc, o, 32);
  if (lane == 0) beta[(size_t)m * NHh + h] = 1.f / (1.f + expf(-acc));
}

// -- eg = exp(-exp(A_log[h]) * softplus(gf + dt_bias)), in place (fallback only) --
__global__ __launch_bounds__(256) void g_kernel(float* __restrict__ gbuf,
                                                const float* __restrict__ dtb,
                                                const float* __restrict__ A_log) {
  const size_t i = (size_t)blockIdx.x * 256 + threadIdx.x;
  const int c = (int)(i % Pp);
  const int h = c / Dd;
  const float xv = gbuf[i] + dtb[c];
  const float sp = (xv > 20.f) ? xv : log1pf(expf(xv));
  gbuf[i] = expf(-expf(A_log[h]) * sp);
}

// ------- depthwise causal conv(K=4) + SiLU (+ optional l2norm) (fallback) -------
__global__ __launch_bounds__(128) void conv_silu_norm(const float* __restrict__ xin,
                                                      const float* __restrict__ w,
                                                      float* __restrict__ out,
                                                      int mode, int instride, int coff) {
  const int idx = blockIdx.x;
  const int h = idx % NHh;
  const int bt = idx / NHh;
  const int t = bt % Tt;
  const int d = threadIdx.x;
  const int c = h * Dd + d;
  float acc = 0.f;
#pragma unroll
  for (int j = 0; j < Kk; j++) {
    const int tt = t - (Kk - 1) + j;
    float xv = 0.f;
    if (tt >= 0) xv = xin[(size_t)(bt - (Kk - 1) + j) * instride + coff + c];
    acc += w[c * Kk + j] * xv;
  }
  float y = acc / (1.f + expf(-acc));
  float r = y;
  if (mode > 0) {
    float ss = y * y;
#pragma unroll
    for (int o = 32; o > 0; o >>= 1) ss += __shfl_down(ss, o);
    __shared__ float red[2];
    if ((d & 63) == 0) red[d >> 6] = ss;
    __syncthreads();
    const float tot = red[0] + red[1];
    const float inv = rsqrtf(tot + EPSf);
    r = y * inv * (mode == 2 ? SCALEf : 1.f);
  }
  out[(size_t)bt * Pp + c] = r;
}

// ------- all three convs, 4 timesteps per block: grid = 3 * (M/4) * NH -------
__global__ __launch_bounds__(128) void conv3b_kernel(const float* __restrict__ qkvpre,
                                                     const float* __restrict__ cq,
                                                     const float* __restrict__ ck,
                                                     const float* __restrict__ cv,
                                                     float* __restrict__ outbase) {
  const int nper = (Bb * Tt / 4) * NHh;   // 4096
  const int which = blockIdx.x / nper;
  const int idx = blockIdx.x % nper;
  const float* w = (which == 0) ? cq : (which == 1) ? ck : cv;
  const int mode = (which == 0) ? 2 : (which == 1) ? 1 : 0;
  const int h = idx % NHh;
  const int bt0 = (idx / NHh) * 4;
  const int t0 = bt0 % Tt;
  const int d = threadIdx.x;
  const int c = h * Dd + d;

  float xw[7];
#pragma unroll
  for (int i = 0; i < 7; i++) {
    const int tt = t0 - 3 + i;
    xw[i] = (tt >= 0) ? qkvpre[(size_t)(bt0 - 3 + i) * (4 * Pp) + which * Pp + c] : 0.f;
  }
  const float w0 = w[c * Kk + 0], w1 = w[c * Kk + 1], w2 = w[c * Kk + 2], w3 = w[c * Kk + 3];
  float y[4];
#pragma unroll
  for (int jj = 0; jj < 4; jj++) {
    const float a = w0 * xw[jj] + w1 * xw[jj + 1] + w2 * xw[jj + 2] + w3 * xw[jj + 3];
    y[jj] = a / (1.f + expf(-a));
  }
  if (mode > 0) {
    float ss[4];
#pragma unroll
    for (int jj = 0; jj < 4; jj++) ss[jj] = y[jj] * y[jj];
#pragma unroll
    for (int o = 32; o > 0; o >>= 1) {
#pragma unroll
      for (int jj = 0; jj < 4; jj++) ss[jj] += __shfl_down(ss[jj], o);
    }
    __shared__ float red[2][4];
    if ((d & 63) == 0) {
#pragma unroll
      for (int jj = 0; jj < 4; jj++) red[d >> 6][jj] = ss[jj];
    }
    __syncthreads();
    const float sc = (mode == 2) ? SCALEf : 1.f;
#pragma unroll
    for (int jj = 0; jj < 4; jj++)
      y[jj] = y[jj] * rsqrtf(red[0][jj] + red[1][jj] + EPSf) * sc;
  }
  float* outp = outbase + (size_t)which * (Bb * Tt) * Pp;
#pragma unroll
  for (int jj = 0; jj < 4; jj++) outp[(size_t)(bt0 + jj) * Pp + c] = y[jj];
}

// ---- gated delta-rule scan: r16 math (packed f32, DPP row16, kt off-chain,
// ---- deferred o-reduce, dbuf) but k/e/q staged by DIRECT global_load_lds
// ---- (size 4, linear [CHUNK][128] rows: lane i of wave w -> element w*64+i).
__global__ __launch_bounds__(128) void scan_kernel(const float* __restrict__ q,
                                                   const float* __restrict__ k,
                                                   const float* __restrict__ v,
                                                   const float* __restrict__ eg,
                                                   const float* __restrict__ beta,
                                                   float* __restrict__ o) {
  const int blk = blockIdx.x;
  const int bh = blk & 15;
  const int dvq = blk >> 4;        // 0..15
  const int b = bh >> 3, h = bh & 7;
  const int tid = threadIdx.x;
  const int qr = tid & 15;
  const int dvl = tid >> 4;        // 0..7
  const int dv = dvq * 8 + dvl;
  const int wv = tid >> 6;         // wave 0/1

  __shared__ __align__(16) float ks[2][CHUNK][Dd];
  __shared__ __align__(16) float legs[2][CHUNK][Dd];
  __shared__ __align__(16) float qs[2][CHUNK][Dd];
  __shared__ float vs[2][CHUNK][8];
  __shared__ float betas[2][CHUNK];

  f32x2 s2[4];
#pragma unroll
  for (int i = 0; i < 4; i++) s2[i] = (f32x2){0.f, 0.f};

  const size_t base = (size_t)(b * Tt) * Pp + h * Dd;
  const int le = tid;

  // async staging of k/e/q straight into LDS (wave-linear dest)
  auto stage = [&](int bufw, int t0) {
    const size_t coff = base + (size_t)t0 * Pp + le;
#pragma unroll
    for (int j = 0; j < CHUNK; j++) {
      gload_lds4(k + coff + (size_t)j * Pp, &ks[bufw][j][wv * 64]);
      gload_lds4(eg + coff + (size_t)j * Pp, &legs[bufw][j][wv * 64]);
      gload_lds4(q + coff + (size_t)j * Pp, &qs[bufw][j][wv * 64]);
    }
  };
  // v / beta: small register path
  float rv[CHUNK], rb = 0.f;
  auto load_vb = [&](int t0) {
    const size_t coff = base + (size_t)t0 * Pp;
    if (tid < 8) {
#pragma unroll
      for (int j = 0; j < CHUNK; j++) rv[j] = v[coff + (size_t)j * Pp + dvq * 8 + tid];
    } else if (tid < 8 + CHUNK) {
      rb = beta[(size_t)(b * Tt + t0 + tid - 8) * NHh + h];
    }
  };
  auto write_vb = [&](int bufw) {
    if (tid < 8) {
#pragma unroll
      for (int j = 0; j < CHUNK; j++) vs[bufw][j][tid] = rv[j];
    } else if (tid < 8 + CHUNK) {
      betas[bufw][tid - 8] = rb;
    }
  };
  auto loadpk = [](const float* p, f32x2 out[4]) {
    const float4 a = *reinterpret_cast<const float4*>(p);
    const float4 b = *reinterpret_cast<const float4*>(p + 4);
    out[0] = (f32x2){a.x, a.y}; out[1] = (f32x2){a.z, a.w};
    out[2] = (f32x2){b.x, b.y}; out[3] = (f32x2){b.z, b.w};
  };

  stage(0, 0);
  load_vb(0);
  write_vb(0);
  __syncthreads();                  // drains gload_lds + vb writes
  const int NC = Tt / CHUNK;
  size_t off = base;
  for (int c = 0; c < NC; c++) {
    if (c + 1 < NC) {
      stage(c & 1 ? 0 : 1, (c + 1) * CHUNK);   // async into other buffer
      load_vb((c + 1) * CHUNK);
    }
    const int buf = c & 1;
    float vv[CHUNK], bb[CHUNK], opart[CHUNK];
#pragma unroll
    for (int j = 0; j < CHUNK; j++) { vv[j] = vs[buf][j][dvl]; bb[j] = betas[buf][j]; }

    f32x2 ck2[4], ce2[4], cq2[4], kt2[4];
    loadpk(&ks[buf][0][qr * 8], ck2);
    loadpk(&legs[buf][0][qr * 8], ce2);
    loadpk(&qs[buf][0][qr * 8], cq2);
#pragma unroll
    for (int i = 0; i < 4; i++) kt2[i] = ck2[i] * ce2[i];

#pragma unroll
    for (int j = 0; j < CHUNK; j++) {
      f32x2 nk[4], ne[4], nq[4];
      if (j + 1 < CHUNK) {                    // prefetch next step's LDS reads
        loadpk(&ks[buf][j + 1][qr * 8], nk);
        loadpk(&legs[buf][j + 1][qr * 8], ne);
        loadpk(&qs[buf][j + 1][qr * 8], nq);
      }
      // decayed state (off the kv chain)
      f32x2 es0 = ce2[0] * s2[0], es1 = ce2[1] * s2[1];
      f32x2 es2v = ce2[2] * s2[2], es3 = ce2[3] * s2[3];
      // kv partials: 2 packed chains
      f32x2 kva = kt2[0] * s2[0];
      f32x2 kvb = kt2[1] * s2[1];
      kva = kt2[2] * s2[2] + kva;
      kvb = kt2[3] * s2[3] + kvb;
      kva = kva + kvb;
      const float kvp = row16_sum(kva.x + kva.y);
      const float delta = (vv[j] - kvp) * bb[j];
      const f32x2 d2 = (f32x2){delta, delta};
      f32x2 o2;
      s2[0] = ck2[0] * d2 + es0;  o2 = cq2[0] * s2[0];
      s2[1] = ck2[1] * d2 + es1;  o2 = cq2[1] * s2[1] + o2;
      s2[2] = ck2[2] * d2 + es2v; o2 = cq2[2] * s2[2] + o2;
      s2[3] = ck2[3] * d2 + es3;  o2 = cq2[3] * s2[3] + o2;
      opart[j] = o2.x + o2.y;                 // reduction deferred
      if (j + 1 < CHUNK) {
#pragma unroll
        for (int i = 0; i < 4; i++) {
          ck2[i] = nk[i]; ce2[i] = ne[i]; cq2[i] = nq[i];
          kt2[i] = ck2[i] * ce2[i];
        }
      }
    }
#pragma unroll
    for (int j = 0; j < CHUNK; j++) opart[j] = row16_sum(opart[j]);
    if (qr == 0) {
#pragma unroll
      for (int j = 0; j < CHUNK; j++) o[off + (size_t)j * Pp + dv] = opart[j];
    }
    if (c + 1 < NC) write_vb(buf ^ 1);
    __syncthreads();                // drains staging; compute of buf done
    off += (size_t)CHUNK * Pp;
  }
}

// ------- og = o * sigmoid(gate); rms-norm over D; * norm_weight -------
__global__ __launch_bounds__(128) void gated_norm(float* __restrict__ o,
                                                  const float* __restrict__ gate,
                                                  int gstride,
                                                  const float* __restrict__ nw,
                                                  __hip_bfloat16* __restrict__ ogbf) {
  const int idx = blockIdx.x;
  const int h = idx % NHh;
  const int bt = idx / NHh;
  const int d = threadIdx.x;
  const size_t off = (size_t)bt * Pp + h * Dd;
  const float ov = o[off + d];
  const float gt = gate[(size_t)bt * gstride + h * Dd + d];
  const float val = ov / (1.f + expf(-gt));
  float ss = val * val;
#pragma unroll
  for (int sh = 32; sh > 0; sh >>= 1) ss += __shfl_down(ss, sh);
  __shared__ float red[2];
  if ((d & 63) == 0) red[d >> 6] = ss;
  __syncthreads();
  const float mean = (red[0] + red[1]) * (1.f / Dd);
  const float res = val * rsqrtf(mean + EPSf) * nw[d];
  if (ogbf != nullptr) ogbf[off + d] = __float2bfloat16(res);
  else o[off + d] = res;
}

extern "C" void kernel_launch(void* const* d_in, const int* in_sizes, int n_in,
                              void* d_out, int out_size, void* d_ws, size_t ws_size,
                              hipStream_t stream) {
  const float* x     = (const float*)d_in[0];
  const float* Wq    = (const float*)d_in[1];
  const float* Wk    = (const float*)d_in[2];
  const float* Wv    = (const float*)d_in[3];
  const float* cq    = (const float*)d_in[4];
  const float* ck    = (const float*)d_in[5];
  const float* cv    = (const float*)d_in[6];
  const float* A_log = (const float*)d_in[7];
  const float* dtb   = (const float*)d_in[8];
  const float* Wfa   = (const float*)d_in[9];
  const float* Wfb   = (const float*)d_in[10];
  const float* Wb    = (const float*)d_in[11];
  const float* Wga   = (const float*)d_in[12];
  const float* Wgb   = (const float*)d_in[13];
  const float* nw    = (const float*)d_in[14];
  const float* Wo    = (const float*)d_in[15];
  float* outp = (float*)d_out;

  const int M = Bb * Tt;          // 2048
  const size_t MP = (size_t)M * Pp;
  float* ws = (float*)d_ws;
  // f32 section
  float* qkvpre = ws;                          // M x 4P (q,k,v,gate)
  float* qb   = qkvpre + 4 * MP;
  float* kb   = qb + MP;
  float* vb   = kb + MP;
  float* gbuf = vb + MP;
  float* obuf = gbuf + MP;
  float* betab = obuf + MP;                    // M*NH
  float* gfa  = betab + (size_t)M * NHh;       // M*D (fallback)
  float* gga  = gfa + (size_t)M * Dd;          // M*D (fallback)
  float* f32end = gga + (size_t)M * Dd;

  // bf16 section
  __hip_bfloat16* xhi    = (__hip_bfloat16*)f32end;
  __hip_bfloat16* xlo    = xhi + (size_t)M * Hh;
  __hip_bfloat16* Wqkvbf = xlo + (size_t)M * Hh;          // 4P x H (q,k,v,gcomb)
  __hip_bfloat16* Wobf   = Wqkvbf + (size_t)4 * Pp * Hh;  // H x P
  __hip_bfloat16* Wcombhi = Wobf + (size_t)Hh * Pp;       // P x H
  __hip_bfloat16* Wcomblo = Wcombhi + (size_t)Pp * Hh;    // P x H
  __hip_bfloat16* end = Wcomblo + (size_t)Pp * Hh;
  __hip_bfloat16* ogbf = xlo;                  // alias: xlo (early) / ogbf (late)
  const bool use_mfma = ws_size >= (size_t)((char*)end - (char*)d_ws);

  const dim3 blk(256);
  if (use_mfma) {
    cvt_split<<<(int)((size_t)M * Hh / 2048), blk, 0, stream>>>(x, xhi, xlo, M * Hh);
    cvt_bf16_x4<<<4 * (int)((size_t)Pp * Hh / 2048), blk, 0, stream>>>(
        Wq, Wk, Wv, Wo, Wqkvbf, Wqkvbf + (size_t)Pp * Hh, Wqkvbf + (size_t)2 * Pp * Hh,
        Wobf, Pp * Hh);
    gemm_nn_split<<<dim3(Hh / 64, Pp / 64), blk, 0, stream>>>(Wfb, Wfa, Wcombhi, Wcomblo,
                                                              Pp, Hh, Dd, 0);
    gemm_nn_split<<<dim3(Hh / 64, Pp / 64), blk, 0, stream>>>(Wgb, Wga,
                                                              Wqkvbf + (size_t)3 * Pp * Hh,
                                                              nullptr, Pp, Hh, Dd, 1);
    gemm_bf16_lds<<<dim3(4 * Pp / 128, M / 128), blk, 0, stream>>>(xhi, Wqkvbf, qkvpre, nullptr,
                                                                   M, 4 * Pp, Hh, 0);
    gemm_bf16_3t_lds<<<dim3(Pp / 128, M / 64), blk, 0, stream>>>(xhi, xlo, Wcombhi, Wcomblo,
                                                                 gbuf, M, Pp, Hh,
                                                                 dtb, A_log, 1);
    beta_kernel<<<M, 256, 0, stream>>>(x, Wb, betab);
    conv3b_kernel<<<3 * (M / 4) * NHh, 128, 0, stream>>>(qkvpre, cq, ck, cv, qb);
    scan_kernel<<<Bb * NHh * DVQ, 128, 0, stream>>>(qb, kb, vb, gbuf, betab, obuf);
    gated_norm<<<M * NHh, 128, 0, stream>>>(obuf, qkvpre + (size_t)3 * Pp, 4 * Pp, nw, ogbf);
    gemm_bf16_lds<<<dim3(Hh / 128, M / 128), blk, 0, stream>>>(ogbf, Wobf, outp, nullptr,
                                                               M, Hh, Pp, 0);
  } else {
    float* qpre = qkvpre;
    float* kpre = qkvpre + MP;
    float* vpre = qkvpre + 2 * MP;
    float* gate = qkvpre + 3 * MP;
    gemm_nt<<<dim3(Pp / 64, M / 64), blk, 0, stream>>>(x, Wq, qpre, M, Pp, Hh);
    gemm_nt<<<dim3(Pp / 64, M / 64), blk, 0, stream>>>(x, Wk, kpre, M, Pp, Hh);
    gemm_nt<<<dim3(Pp / 64, M / 64), blk, 0, stream>>>(x, Wv, vpre, M, Pp, Hh);
    gemm_nt<<<dim3(Dd / 64, M / 64), blk, 0, stream>>>(x, Wfa, gfa, M, Dd, Hh);
    gemm_nt<<<dim3(Dd / 64, M / 64), blk, 0, stream>>>(x, Wga, gga, M, Dd, Hh);
    gemm_nt<<<dim3(Pp / 64, M / 64), blk, 0, stream>>>(gfa, Wfb, gbuf, M, Pp, Dd);
    gemm_nt<<<dim3(Pp / 64, M / 64), blk, 0, stream>>>(gga, Wgb, gate, M, Pp, Dd);
    beta_kernel<<<M, 256, 0, stream>>>(x, Wb, betab);
    g_kernel<<<(int)(MP / 256), 256, 0, stream>>>(gbuf, dtb, A_log);
    conv_silu_norm<<<M * NHh, 128, 0, stream>>>(qpre, cq, qb, 2, Pp, 0);
    conv_silu_norm<<<M * NHh, 128, 0, stream>>>(kpre, ck, kb, 1, Pp, 0);
    conv_silu_norm<<<M * NHh, 128, 0, stream>>>(vpre, cv, vb, 0, Pp, 0);
    scan_kernel<<<Bb * NHh * DVQ, 128, 0, stream>>>(qb, kb, vb, gbuf, betab, obuf);
    gated_norm<<<M * NHh, 128, 0, stream>>>(obuf, gate, Pp, nw, nullptr);
    gemm_nt<<<dim3(Hh / 64, M / 64), blk, 0, stream>>>(obuf, Wo, outp, M, Hh, Pp);
  }
}

// Round 19
// 446.351 us; speedup vs baseline: 1.0614x; 1.0614x over previous
//
#include <hip/hip_runtime.h>
#include <hip/hip_bf16.h>
#include <cstddef>
#include <cstdint>

#define Bb 2
#define Tt 1024
#define Hh 2048
#define NHh 8
#define Dd 128
#define Pp (NHh * Dd)   // 1024
#define Kk 4
#define EPSf 1e-6f
#define SCALEf 0.08838834764831845f  // D^-0.5
#define DVQ 16          // dv-splits per (b,h): 16 blocks x 8 columns
#define CHUNK 8         // timesteps per barrier round in scan

typedef short bf16x8 __attribute__((ext_vector_type(8)));
typedef float f32x4 __attribute__((ext_vector_type(4)));
typedef float f32x2 __attribute__((ext_vector_type(2)));   // -> v_pk_*_f32

// DPP rotate-add: 16-lane row sum in 4 VALU ops (all lanes get the sum).
template <int CTRL>
__device__ __forceinline__ float dpp_add(float x) {
  int yi = __builtin_amdgcn_update_dpp(0, __builtin_bit_cast(int, x), CTRL, 0xF, 0xF, true);
  return x + __builtin_bit_cast(float, yi);
}
__device__ __forceinline__ float row16_sum(float x) {
  x = dpp_add<0xB1>(x);
  x = dpp_add<0x4E>(x);
  x = dpp_add<0x124>(x);
  x = dpp_add<0x128>(x);
  return x;
}

// async global->LDS, 16B per lane; lds base must be wave-uniform (HW adds lane*16).
__device__ __forceinline__ void gload_lds16(const void* g, void* l) {
  __builtin_amdgcn_global_load_lds((const __attribute__((address_space(1))) void*)g,
                                   (__attribute__((address_space(3))) void*)l, 16, 0, 0);
}

// ---------------- f32 -> bf16 convert (8 elems/thread) ----------------
__global__ __launch_bounds__(256) void cvt_bf16(const float* __restrict__ src,
                                                __hip_bfloat16* __restrict__ dst, int n) {
  const int i = (blockIdx.x * 256 + threadIdx.x) * 8;
  if (i >= n) return;
  const float4 a = *reinterpret_cast<const float4*>(src + i);
  const float4 b = *reinterpret_cast<const float4*>(src + i + 4);
  __hip_bfloat16 t[8];
  t[0] = __float2bfloat16(a.x); t[1] = __float2bfloat16(a.y);
  t[2] = __float2bfloat16(a.z); t[3] = __float2bfloat16(a.w);
  t[4] = __float2bfloat16(b.x); t[5] = __float2bfloat16(b.y);
  t[6] = __float2bfloat16(b.z); t[7] = __float2bfloat16(b.w);
  *reinterpret_cast<uint4*>(dst + i) = *reinterpret_cast<const uint4*>(t);
}

// ---------------- 4-array f32 -> bf16 (fused weight conversion) ----------------
__global__ __launch_bounds__(256) void cvt_bf16_x4(const float* __restrict__ s0,
                                                   const float* __restrict__ s1,
                                                   const float* __restrict__ s2,
                                                   const float* __restrict__ s3,
                                                   __hip_bfloat16* __restrict__ d0,
                                                   __hip_bfloat16* __restrict__ d1,
                                                   __hip_bfloat16* __restrict__ d2,
                                                   __hip_bfloat16* __restrict__ d3,
                                                   int nper) {
  const int bpa = nper / 2048;
  const int a = blockIdx.x / bpa;
  const int i = (blockIdx.x % bpa) * 2048 + threadIdx.x * 8;
  const float* src = (a == 0) ? s0 : (a == 1) ? s1 : (a == 2) ? s2 : s3;
  __hip_bfloat16* dst = (a == 0) ? d0 : (a == 1) ? d1 : (a == 2) ? d2 : d3;
  const float4 x = *reinterpret_cast<const float4*>(src + i);
  const float4 y = *reinterpret_cast<const float4*>(src + i + 4);
  __hip_bfloat16 t[8];
  t[0] = __float2bfloat16(x.x); t[1] = __float2bfloat16(x.y);
  t[2] = __float2bfloat16(x.z); t[3] = __float2bfloat16(x.w);
  t[4] = __float2bfloat16(y.x); t[5] = __float2bfloat16(y.y);
  t[6] = __float2bfloat16(y.z); t[7] = __float2bfloat16(y.w);
  *reinterpret_cast<uint4*>(dst + i) = *reinterpret_cast<const uint4*>(t);
}

// ---------------- f32 -> (hi, lo) bf16 split ----------------
__global__ __launch_bounds__(256) void cvt_split(const float* __restrict__ src,
                                                 __hip_bfloat16* __restrict__ hi,
                                                 __hip_bfloat16* __restrict__ lo, int n) {
  const int i = (blockIdx.x * 256 + threadIdx.x) * 8;
  if (i >= n) return;
  __hip_bfloat16 th[8], tl[8];
#pragma unroll
  for (int j = 0; j < 2; j++) {
    const float4 a = *reinterpret_cast<const float4*>(src + i + j * 4);
    const float f[4] = {a.x, a.y, a.z, a.w};
#pragma unroll
    for (int e = 0; e < 4; e++) {
      const __hip_bfloat16 h = __float2bfloat16(f[e]);
      th[j * 4 + e] = h;
      tl[j * 4 + e] = __float2bfloat16(f[e] - __bfloat162float(h));
    }
  }
  *reinterpret_cast<uint4*>(hi + i) = *reinterpret_cast<const uint4*>(th);
  *reinterpret_cast<uint4*>(lo + i) = *reinterpret_cast<const uint4*>(tl);
}

// ---- NN f32 GEMM with bf16(-split) output: C[M,N] = A[M,K] @ B[K,N] ----
// mode 0: write Chi/Clo (hi/lo split); mode 1: write Chi only. Exact f32 accumulate.
__global__ __launch_bounds__(256) void gemm_nn_split(const float* __restrict__ A,
                                                     const float* __restrict__ B,
                                                     __hip_bfloat16* __restrict__ Chi,
                                                     __hip_bfloat16* __restrict__ Clo,
                                                     int M, int N, int K, int mode) {
  __shared__ float As[64][33];
  __shared__ float Bs[32][65];
  const int bm = blockIdx.y * 64, bn = blockIdx.x * 64;
  const int tid = threadIdx.x;
  const int tx = tid & 15, ty = tid >> 4;
  float acc[4][4];
#pragma unroll
  for (int i = 0; i < 4; i++)
#pragma unroll
    for (int j = 0; j < 4; j++) acc[i][j] = 0.f;
  for (int k0 = 0; k0 < K; k0 += 32) {
#pragma unroll
    for (int i = 0; i < 8; i++) {
      const int idx = tid + i * 256;            // 0..2047
      const int r = idx >> 5, c = idx & 31;     // A: 64 x 32
      As[r][c] = A[(size_t)(bm + r) * K + k0 + c];
    }
#pragma unroll
    for (int i = 0; i < 8; i++) {
      const int idx = tid + i * 256;
      const int r = idx >> 6, c = idx & 63;     // B: 32 x 64
      Bs[r][c] = B[(size_t)(k0 + r) * N + bn + c];
    }
    __syncthreads();
#pragma unroll
    for (int kk = 0; kk < 32; kk++) {
      float a[4], b[4];
#pragma unroll
      for (int i = 0; i < 4; i++) a[i] = As[ty * 4 + i][kk];
#pragma unroll
      for (int j = 0; j < 4; j++) b[j] = Bs[kk][tx * 4 + j];
#pragma unroll
      for (int i = 0; i < 4; i++)
#pragma unroll
        for (int j = 0; j < 4; j++) acc[i][j] += a[i] * b[j];
    }
    __syncthreads();
  }
#pragma unroll
  for (int i = 0; i < 4; i++) {
    const int row = bm + ty * 4 + i;
#pragma unroll
    for (int j = 0; j < 4; j++) {
      const int col = bn + tx * 4 + j;
      const float v = acc[i][j];
      const __hip_bfloat16 h = __float2bfloat16(v);
      Chi[(size_t)row * N + col] = h;
      if (mode == 0) Clo[(size_t)row * N + col] = __float2bfloat16(v - __bfloat162float(h));
    }
  }
}

// ------ bf16 MFMA NT GEMM via global_load_lds (m97 structure): 128x128, BK=64 ------
__global__ __launch_bounds__(256) void gemm_bf16_lds(const __hip_bfloat16* __restrict__ A,
                                                     const __hip_bfloat16* __restrict__ B,
                                                     float* __restrict__ C,
                                                     __hip_bfloat16* __restrict__ Cbf,
                                                     int M, int N, int K, int outmode) {
  __shared__ __align__(16) __hip_bfloat16 As[128 * 64];
  __shared__ __align__(16) __hip_bfloat16 Bs[128 * 64];
  const int tid = threadIdx.x;
  const int wave = tid >> 6;
  const int lane = tid & 63;
  const int wm = (wave >> 1) * 64;
  const int wn = (wave & 1) * 64;
  const int bm = blockIdx.y * 128;
  const int bn = blockIdx.x * 128;
  const int l15 = lane & 15;
  const int l4 = lane >> 4;
  const int srow = lane >> 3;
  const int scol = (lane & 7) * 8;

  f32x4 acc[4][4];
#pragma unroll
  for (int i = 0; i < 4; i++)
#pragma unroll
    for (int j = 0; j < 4; j++) acc[i][j] = (f32x4){0.f, 0.f, 0.f, 0.f};

  for (int k0 = 0; k0 < K; k0 += 64) {
#pragma unroll
    for (int i = 0; i < 4; i++) {
      const int s = wave * 4 + i;
      const int row = s * 8 + srow;
      gload_lds16(A + (size_t)(bm + row) * K + k0 + scol, &As[s * 512]);
      gload_lds16(B + (size_t)(bn + row) * K + k0 + scol, &Bs[s * 512]);
    }
    __syncthreads();
    bf16x8 af[4][2], bfv[4][2];
#pragma unroll
    for (int kf = 0; kf < 2; kf++) {
      const int kc = kf * 32 + l4 * 8;
#pragma unroll
      for (int mf = 0; mf < 4; mf++)
        af[mf][kf] = *reinterpret_cast<const bf16x8*>(&As[(wm + mf * 16 + l15) * 64 + kc]);
#pragma unroll
      for (int nf = 0; nf < 4; nf++)
        bfv[nf][kf] = *reinterpret_cast<const bf16x8*>(&Bs[(wn + nf * 16 + l15) * 64 + kc]);
    }
#pragma unroll
    for (int kf = 0; kf < 2; kf++)
#pragma unroll
      for (int mf = 0; mf < 4; mf++)
#pragma unroll
        for (int nf = 0; nf < 4; nf++)
          acc[mf][nf] = __builtin_amdgcn_mfma_f32_16x16x32_bf16(af[mf][kf], bfv[nf][kf],
                                                                acc[mf][nf], 0, 0, 0);
    __syncthreads();
  }
#pragma unroll
  for (int mf = 0; mf < 4; mf++) {
#pragma unroll
    for (int nf = 0; nf < 4; nf++) {
      const int col = bn + wn + nf * 16 + l15;
#pragma unroll
      for (int r = 0; r < 4; r++) {
        const int row = bm + wm + mf * 16 + l4 * 4 + r;
        if (outmode == 0) C[(size_t)row * N + col] = acc[mf][nf][r];
        else Cbf[(size_t)row * N + col] = __float2bfloat16(acc[mf][nf][r]);
      }
    }
  }
}

// -- 3-term split-bf16 MFMA NT GEMM via global_load_lds: C = AhBh + AhBl + AlBh --
// BM=64, BN=128, BK=64. gmode=1: fuse eg = exp(-exp(A_log)*softplus(acc+dtb)).
__global__ __launch_bounds__(256) void gemm_bf16_3t_lds(const __hip_bfloat16* __restrict__ Ahi,
                                                        const __hip_bfloat16* __restrict__ Alo,
                                                        const __hip_bfloat16* __restrict__ Bhi,
                                                        const __hip_bfloat16* __restrict__ Blo,
                                                        float* __restrict__ C,
                                                        int M, int N, int K,
                                                        const float* __restrict__ dtb,
                                                        const float* __restrict__ A_log,
                                                        int gmode) {
  __shared__ __align__(16) __hip_bfloat16 Ahs[64 * 64];
  __shared__ __align__(16) __hip_bfloat16 Als[64 * 64];
  __shared__ __align__(16) __hip_bfloat16 Bhs[128 * 64];
  __shared__ __align__(16) __hip_bfloat16 Bls[128 * 64];
  const int tid = threadIdx.x;
  const int wave = tid >> 6;
  const int lane = tid & 63;
  const int wm = (wave >> 1) * 32;   // 0 or 32
  const int wn = (wave & 1) * 64;    // 0 or 64
  const int bm = blockIdx.y * 64;
  const int bn = blockIdx.x * 128;
  const int l15 = lane & 15;
  const int l4 = lane >> 4;
  const int srow = lane >> 3;
  const int scol = (lane & 7) * 8;

  f32x4 acc[2][4];
#pragma unroll
  for (int i = 0; i < 2; i++)
#pragma unroll
    for (int j = 0; j < 4; j++) acc[i][j] = (f32x4){0.f, 0.f, 0.f, 0.f};

  for (int k0 = 0; k0 < K; k0 += 64) {
#pragma unroll
    for (int i = 0; i < 12; i++) {
      const int sid = wave * 12 + i;        // 0..47, wave-uniform
      if (sid < 8) {
        const int row = sid * 8 + srow;
        gload_lds16(Ahi + (size_t)(bm + row) * K + k0 + scol, &Ahs[sid * 512]);
      } else if (sid < 16) {
        const int row = (sid - 8) * 8 + srow;
        gload_lds16(Alo + (size_t)(bm + row) * K + k0 + scol, &Als[(sid - 8) * 512]);
      } else if (sid < 32) {
        const int row = (sid - 16) * 8 + srow;
        gload_lds16(Bhi + (size_t)(bn + row) * K + k0 + scol, &Bhs[(sid - 16) * 512]);
      } else {
        const int row = (sid - 32) * 8 + srow;
        gload_lds16(Blo + (size_t)(bn + row) * K + k0 + scol, &Bls[(sid - 32) * 512]);
      }
    }
    __syncthreads();
#pragma unroll
    for (int kf = 0; kf < 2; kf++) {
      const int kc = kf * 32 + l4 * 8;
      bf16x8 ah[2], al[2], bh[4], bl[4];
#pragma unroll
      for (int mf = 0; mf < 2; mf++) {
        ah[mf] = *reinterpret_cast<const bf16x8*>(&Ahs[(wm + mf * 16 + l15) * 64 + kc]);
        al[mf] = *reinterpret_cast<const bf16x8*>(&Als[(wm + mf * 16 + l15) * 64 + kc]);
      }
#pragma unroll
      for (int nf = 0; nf < 4; nf++) {
        bh[nf] = *reinterpret_cast<const bf16x8*>(&Bhs[(wn + nf * 16 + l15) * 64 + kc]);
        bl[nf] = *reinterpret_cast<const bf16x8*>(&Bls[(wn + nf * 16 + l15) * 64 + kc]);
      }
#pragma unroll
      for (int mf = 0; mf < 2; mf++)
#pragma unroll
        for (int nf = 0; nf < 4; nf++) {
          acc[mf][nf] = __builtin_amdgcn_mfma_f32_16x16x32_bf16(ah[mf], bh[nf], acc[mf][nf], 0, 0, 0);
          acc[mf][nf] = __builtin_amdgcn_mfma_f32_16x16x32_bf16(ah[mf], bl[nf], acc[mf][nf], 0, 0, 0);
          acc[mf][nf] = __builtin_amdgcn_mfma_f32_16x16x32_bf16(al[mf], bh[nf], acc[mf][nf], 0, 0, 0);
        }
    }
    __syncthreads();
  }
#pragma unroll
  for (int mf = 0; mf < 2; mf++)
#pragma unroll
    for (int nf = 0; nf < 4; nf++) {
      const int col = bn + wn + nf * 16 + l15;
#pragma unroll
      for (int r = 0; r < 4; r++) {
        const int row = bm + wm + mf * 16 + l4 * 4 + r;
        float val = acc[mf][nf][r];
        if (gmode) {   // eg = exp(-exp(A_log[h]) * softplus(val + dtb[col]))
          const float xv = val + dtb[col];
          const float sp = (xv > 20.f) ? xv : log1pf(expf(xv));
          val = expf(-expf(A_log[col >> 7]) * sp);
        }
        C[(size_t)row * N + col] = val;
      }
    }
}

// ---------------- generic f32 GEMM (fallback only) ----------------
__global__ __launch_bounds__(256) void gemm_nt(const float* __restrict__ A,
                                               const float* __restrict__ Bm,
                                               float* __restrict__ C,
                                               int M, int N, int Kd) {
  __shared__ float As[16][64];
  __shared__ float Bs[16][64];
  const int bm = blockIdx.y * 64;
  const int bn = blockIdx.x * 64;
  const int tid = threadIdx.x;
  const int tx = tid & 15;
  const int ty = tid >> 4;
  const int lr = tid >> 2;
  const int lc = (tid & 3) << 2;
  float acc[4][4];
#pragma unroll
  for (int i = 0; i < 4; i++)
#pragma unroll
    for (int j = 0; j < 4; j++) acc[i][j] = 0.f;
  for (int k0 = 0; k0 < Kd; k0 += 16) {
    float4 a4 = make_float4(0.f, 0.f, 0.f, 0.f);
    float4 b4 = make_float4(0.f, 0.f, 0.f, 0.f);
    const int ar = bm + lr;
    if (ar < M) a4 = *reinterpret_cast<const float4*>(A + (size_t)ar * Kd + k0 + lc);
    const int br = bn + lr;
    if (br < N) b4 = *reinterpret_cast<const float4*>(Bm + (size_t)br * Kd + k0 + lc);
    As[lc + 0][lr] = a4.x; As[lc + 1][lr] = a4.y; As[lc + 2][lr] = a4.z; As[lc + 3][lr] = a4.w;
    Bs[lc + 0][lr] = b4.x; Bs[lc + 1][lr] = b4.y; Bs[lc + 2][lr] = b4.z; Bs[lc + 3][lr] = b4.w;
    __syncthreads();
#pragma unroll
    for (int kk = 0; kk < 16; kk++) {
      float4 av = *reinterpret_cast<const float4*>(&As[kk][ty << 2]);
      float4 bv = *reinterpret_cast<const float4*>(&Bs[kk][tx << 2]);
      float a[4] = {av.x, av.y, av.z, av.w};
      float b[4] = {bv.x, bv.y, bv.z, bv.w};
#pragma unroll
      for (int i = 0; i < 4; i++)
#pragma unroll
        for (int j = 0; j < 4; j++) acc[i][j] += a[i] * b[j];
    }
    __syncthreads();
  }
#pragma unroll
  for (int i = 0; i < 4; i++) {
    const int row = bm + (ty << 2) + i;
    if (row >= M) continue;
#pragma unroll
    for (int j = 0; j < 4; j++) {
      const int col = bn + (tx << 2) + j;
      if (col < N) C[(size_t)row * N + col] = acc[i][j];
    }
  }
}

// ---------------- beta = sigmoid(x @ Wb^T), Wb (NH,H) ----------------
__global__ __launch_bounds__(256) void beta_kernel(const float* __restrict__ x,
                                                   const float* __restrict__ Wb,
                                                   float* __restrict__ beta) {
  __shared__ float xs[Hh];
  const int m = blockIdx.x;
  const int tid = threadIdx.x;
  for (int i = tid; i < Hh; i += 256) xs[i] = x[(size_t)m * Hh + i];
  __syncthreads();
  const int h = tid >> 5;
  const int lane = tid & 31;
  float acc = 0.f;
  for (int i = lane; i < Hh; i += 32) acc += xs[i] * Wb[(size_t)h * Hh + i];
#pragma unroll
  for (int o = 16; o > 0; o >>= 1) acc += __shfl_down(acc, o, 32);
  if (lane == 0) beta[(size_t)m * NHh + h] = 1.f / (1.f + expf(-acc));
}

// -- eg = exp(-exp(A_log[h]) * softplus(gf + dt_bias)), in place (fallback only) --
__global__ __launch_bounds__(256) void g_kernel(float* __restrict__ gbuf,
                                                const float* __restrict__ dtb,
                                                const float* __restrict__ A_log) {
  const size_t i = (size_t)blockIdx.x * 256 + threadIdx.x;
  const int c = (int)(i % Pp);
  const int h = c / Dd;
  const float xv = gbuf[i] + dtb[c];
  const float sp = (xv > 20.f) ? xv : log1pf(expf(xv));
  gbuf[i] = expf(-expf(A_log[h]) * sp);
}

// ------- depthwise causal conv(K=4) + SiLU (+ optional l2norm) (fallback) -------
__global__ __launch_bounds__(128) void conv_silu_norm(const float* __restrict__ xin,
                                                      const float* __restrict__ w,
                                                      float* __restrict__ out,
                                                      int mode, int instride, int coff) {
  const int idx = blockIdx.x;            // (b*T + t)*NH + h
  const int h = idx % NHh;
  const int bt = idx / NHh;
  const int t = bt % Tt;
  const int d = threadIdx.x;
  const int c = h * Dd + d;
  float acc = 0.f;
#pragma unroll
  for (int j = 0; j < Kk; j++) {
    const int tt = t - (Kk - 1) + j;
    float xv = 0.f;
    if (tt >= 0) xv = xin[(size_t)(bt - (Kk - 1) + j) * instride + coff + c];
    acc += w[c * Kk + j] * xv;
  }
  float y = acc / (1.f + expf(-acc));    // silu
  float r = y;
  if (mode > 0) {
    float ss = y * y;
#pragma unroll
    for (int o = 32; o > 0; o >>= 1) ss += __shfl_down(ss, o);
    __shared__ float red[2];
    if ((d & 63) == 0) red[d >> 6] = ss;
    __syncthreads();
    const float tot = red[0] + red[1];
    const float inv = rsqrtf(tot + EPSf);
    r = y * inv * (mode == 2 ? SCALEf : 1.f);
  }
  out[(size_t)bt * Pp + c] = r;
}

// ------- all three convs, 4 timesteps per block: grid = 3 * (M/4) * NH -------
__global__ __launch_bounds__(128) void conv3b_kernel(const float* __restrict__ qkvpre,
                                                     const float* __restrict__ cq,
                                                     const float* __restrict__ ck,
                                                     const float* __restrict__ cv,
                                                     float* __restrict__ outbase) {
  const int nper = (Bb * Tt / 4) * NHh;   // 4096
  const int which = blockIdx.x / nper;    // 0:q 1:k 2:v
  const int idx = blockIdx.x % nper;
  const float* w = (which == 0) ? cq : (which == 1) ? ck : cv;
  const int mode = (which == 0) ? 2 : (which == 1) ? 1 : 0;
  const int h = idx % NHh;
  const int bt0 = (idx / NHh) * 4;        // 4-aligned, never crosses batch
  const int t0 = bt0 % Tt;
  const int d = threadIdx.x;
  const int c = h * Dd + d;

  float xw[7];
#pragma unroll
  for (int i = 0; i < 7; i++) {
    const int tt = t0 - 3 + i;
    xw[i] = (tt >= 0) ? qkvpre[(size_t)(bt0 - 3 + i) * (4 * Pp) + which * Pp + c] : 0.f;
  }
  const float w0 = w[c * Kk + 0], w1 = w[c * Kk + 1], w2 = w[c * Kk + 2], w3 = w[c * Kk + 3];
  float y[4];
#pragma unroll
  for (int jj = 0; jj < 4; jj++) {
    const float a = w0 * xw[jj] + w1 * xw[jj + 1] + w2 * xw[jj + 2] + w3 * xw[jj + 3];
    y[jj] = a / (1.f + expf(-a));   // silu
  }
  if (mode > 0) {
    float ss[4];
#pragma unroll
    for (int jj = 0; jj < 4; jj++) ss[jj] = y[jj] * y[jj];
#pragma unroll
    for (int o = 32; o > 0; o >>= 1) {
#pragma unroll
      for (int jj = 0; jj < 4; jj++) ss[jj] += __shfl_down(ss[jj], o);
    }
    __shared__ float red[2][4];
    if ((d & 63) == 0) {
#pragma unroll
      for (int jj = 0; jj < 4; jj++) red[d >> 6][jj] = ss[jj];
    }
    __syncthreads();
    const float sc = (mode == 2) ? SCALEf : 1.f;
#pragma unroll
    for (int jj = 0; jj < 4; jj++)
      y[jj] = y[jj] * rsqrtf(red[0][jj] + red[1][jj] + EPSf) * sc;
  }
  float* outp = outbase + (size_t)which * (Bb * Tt) * Pp;
#pragma unroll
  for (int jj = 0; jj < 4; jj++) outp[(size_t)(bt0 + jj) * Pp + c] = y[jj];
}

// ---- gated delta-rule scan (r11-proven): packed-f32 math, double-buffered LDS,
// ---- 1-step reg pipeline, kt=k*e off-chain, s = pk_fma(k, delta, e*s).
__global__ __launch_bounds__(128) void scan_kernel(const float* __restrict__ q,
                                                   const float* __restrict__ k,
                                                   const float* __restrict__ v,
                                                   const float* __restrict__ eg,
                                                   const float* __restrict__ beta,
                                                   float* __restrict__ o) {
  const int blk = blockIdx.x;
  const int bh = blk & 15;
  const int dvq = blk >> 4;        // 0..15
  const int b = bh >> 3, h = bh & 7;
  const int tid = threadIdx.x;
  const int qr = tid & 15;
  const int dvl = tid >> 4;        // 0..7
  const int dv = dvq * 8 + dvl;

  __shared__ __align__(16) float qs[2][CHUNK][16][12];
  __shared__ __align__(16) float ks[2][CHUNK][16][12];
  __shared__ __align__(16) float legs[2][CHUNK][16][12];
  __shared__ float vs[2][CHUNK][8];
  __shared__ float betas[2][CHUNK];

  f32x2 s2[4];
#pragma unroll
  for (int i = 0; i < 4; i++) s2[i] = (f32x2){0.f, 0.f};

  const size_t base = (size_t)(b * Tt) * Pp + h * Dd;
  const int le = tid;

  float rq[CHUNK], rk[CHUNK], re[CHUNK], rv[CHUNK], rb = 0.f;
  auto load_chunk = [&](int t0) {
    const size_t coff = base + (size_t)t0 * Pp;
#pragma unroll
    for (int j = 0; j < CHUNK; j++) {
      rq[j] = q[coff + (size_t)j * Pp + le];
      rk[j] = k[coff + (size_t)j * Pp + le];
      re[j] = eg[coff + (size_t)j * Pp + le];
    }
    if (tid < 8) {
#pragma unroll
      for (int j = 0; j < CHUNK; j++) rv[j] = v[coff + (size_t)j * Pp + dvq * 8 + tid];
    } else if (tid < 8 + CHUNK) {
      rb = beta[(size_t)(b * Tt + t0 + tid - 8) * NHh + h];
    }
  };
  auto write_lds = [&](int bufw) {
#pragma unroll
    for (int j = 0; j < CHUNK; j++) {
      qs[bufw][j][le >> 3][le & 7] = rq[j];
      ks[bufw][j][le >> 3][le & 7] = rk[j];
      legs[bufw][j][le >> 3][le & 7] = re[j];
    }
    if (tid < 8) {
#pragma unroll
      for (int j = 0; j < CHUNK; j++) vs[bufw][j][tid] = rv[j];
    } else if (tid < 8 + CHUNK) {
      betas[bufw][tid - 8] = rb;
    }
  };
  auto unpack = [](const float4& a, const float4& b, f32x2 out[4]) {
    out[0] = (f32x2){a.x, a.y}; out[1] = (f32x2){a.z, a.w};
    out[2] = (f32x2){b.x, b.y}; out[3] = (f32x2){b.z, b.w};
  };

  load_chunk(0);
  write_lds(0);
  __syncthreads();
  const int NC = Tt / CHUNK;
  size_t off = base;
  for (int c = 0; c < NC; c++) {
    if (c + 1 < NC) load_chunk((c + 1) * CHUNK);  // global latency hides under compute
    const int buf = c & 1;
    float vv[CHUNK], bb[CHUNK], opart[CHUNK];
#pragma unroll
    for (int j = 0; j < CHUNK; j++) { vv[j] = vs[buf][j][dvl]; bb[j] = betas[buf][j]; }

    f32x2 ck2[4], ce2[4], cq2[4], kt2[4];
    {
      const float4 k0 = *reinterpret_cast<const float4*>(&ks[buf][0][qr][0]);
      const float4 k1 = *reinterpret_cast<const float4*>(&ks[buf][0][qr][4]);
      const float4 e0 = *reinterpret_cast<const float4*>(&legs[buf][0][qr][0]);
      const float4 e1 = *reinterpret_cast<const float4*>(&legs[buf][0][qr][4]);
      const float4 q0 = *reinterpret_cast<const float4*>(&qs[buf][0][qr][0]);
      const float4 q1 = *reinterpret_cast<const float4*>(&qs[buf][0][qr][4]);
      unpack(k0, k1, ck2); unpack(e0, e1, ce2); unpack(q0, q1, cq2);
#pragma unroll
      for (int i = 0; i < 4; i++) kt2[i] = ck2[i] * ce2[i];
    }

#pragma unroll
    for (int j = 0; j < CHUNK; j++) {
      float4 nk0, nk1, ne0, ne1, nq0, nq1;
      if (j + 1 < CHUNK) {                    // prefetch next step's LDS reads
        nk0 = *reinterpret_cast<const float4*>(&ks[buf][j + 1][qr][0]);
        nk1 = *reinterpret_cast<const float4*>(&ks[buf][j + 1][qr][4]);
        ne0 = *reinterpret_cast<const float4*>(&legs[buf][j + 1][qr][0]);
        ne1 = *reinterpret_cast<const float4*>(&legs[buf][j + 1][qr][4]);
        nq0 = *reinterpret_cast<const float4*>(&qs[buf][j + 1][qr][0]);
        nq1 = *reinterpret_cast<const float4*>(&qs[buf][j + 1][qr][4]);
      }
      // decayed state (off the kv chain)
      f32x2 es0 = ce2[0] * s2[0], es1 = ce2[1] * s2[1];
      f32x2 es2v = ce2[2] * s2[2], es3 = ce2[3] * s2[3];
      // kv partials: 2 packed chains
      f32x2 kva = kt2[0] * s2[0];
      f32x2 kvb = kt2[1] * s2[1];
      kva = kt2[2] * s2[2] + kva;
      kvb = kt2[3] * s2[3] + kvb;
      kva = kva + kvb;
      const float kvp = row16_sum(kva.x + kva.y);
      const float delta = (vv[j] - kvp) * bb[j];
      const f32x2 d2 = (f32x2){delta, delta};
      f32x2 o2;
      s2[0] = ck2[0] * d2 + es0;  o2 = cq2[0] * s2[0];
      s2[1] = ck2[1] * d2 + es1;  o2 = cq2[1] * s2[1] + o2;
      s2[2] = ck2[2] * d2 + es2v; o2 = cq2[2] * s2[2] + o2;
      s2[3] = ck2[3] * d2 + es3;  o2 = cq2[3] * s2[3] + o2;
      opart[j] = o2.x + o2.y;                 // reduction deferred
      if (j + 1 < CHUNK) {
        unpack(nk0, nk1, ck2); unpack(ne0, ne1, ce2); unpack(nq0, nq1, cq2);
#pragma unroll
        for (int i = 0; i < 4; i++) kt2[i] = ck2[i] * ce2[i];
      }
    }
#pragma unroll
    for (int j = 0; j < CHUNK; j++) opart[j] = row16_sum(opart[j]);
    if (qr == 0) {
#pragma unroll
      for (int j = 0; j < CHUNK; j++) o[off + (size_t)j * Pp + dv] = opart[j];
    }
    if (c + 1 < NC) write_lds(buf ^ 1);       // other buffer: no pre-barrier needed
    __syncthreads();
    off += (size_t)CHUNK * Pp;
  }
}

// ------- og = o * sigmoid(gate); rms-norm over D; * norm_weight -------
__global__ __launch_bounds__(128) void gated_norm(float* __restrict__ o,
                                                  const float* __restrict__ gate,
                                                  int gstride,
                                                  const float* __restrict__ nw,
                                                  __hip_bfloat16* __restrict__ ogbf) {
  const int idx = blockIdx.x;
  const int h = idx % NHh;
  const int bt = idx / NHh;
  const int d = threadIdx.x;
  const size_t off = (size_t)bt * Pp + h * Dd;
  const float ov = o[off + d];
  const float gt = gate[(size_t)bt * gstride + h * Dd + d];
  const float val = ov / (1.f + expf(-gt));
  float ss = val * val;
#pragma unroll
  for (int sh = 32; sh > 0; sh >>= 1) ss += __shfl_down(ss, sh);
  __shared__ float red[2];
  if ((d & 63) == 0) red[d >> 6] = ss;
  __syncthreads();
  const float mean = (red[0] + red[1]) * (1.f / Dd);
  const float res = val * rsqrtf(mean + EPSf) * nw[d];
  if (ogbf != nullptr) ogbf[off + d] = __float2bfloat16(res);
  else o[off + d] = res;
}

extern "C" void kernel_launch(void* const* d_in, const int* in_sizes, int n_in,
                              void* d_out, int out_size, void* d_ws, size_t ws_size,
                              hipStream_t stream) {
  const float* x     = (const float*)d_in[0];
  const float* Wq    = (const float*)d_in[1];
  const float* Wk    = (const float*)d_in[2];
  const float* Wv    = (const float*)d_in[3];
  const float* cq    = (const float*)d_in[4];
  const float* ck    = (const float*)d_in[5];
  const float* cv    = (const float*)d_in[6];
  const float* A_log = (const float*)d_in[7];
  const float* dtb   = (const float*)d_in[8];
  const float* Wfa   = (const float*)d_in[9];
  const float* Wfb   = (const float*)d_in[10];
  const float* Wb    = (const float*)d_in[11];
  const float* Wga   = (const float*)d_in[12];
  const float* Wgb   = (const float*)d_in[13];
  const float* nw    = (const float*)d_in[14];
  const float* Wo    = (const float*)d_in[15];
  float* outp = (float*)d_out;

  const int M = Bb * Tt;          // 2048
  const size_t MP = (size_t)M * Pp;
  float* ws = (float*)d_ws;
  // f32 section (layout identical to r11)
  float* qkvpre = ws;                          // M x 4P (q,k,v,gate)
  float* qb   = qkvpre + 4 * MP;
  float* kb   = qb + MP;
  float* vb   = kb + MP;
  float* gbuf = vb + MP;
  float* obuf = gbuf + MP;
  float* betab = obuf + MP;                    // M*NH
  float* gfa  = betab + (size_t)M * NHh;       // M*D (fallback)
  float* gga  = gfa + (size_t)M * Dd;          // M*D (fallback)
  float* f32end = gga + (size_t)M * Dd;

  // bf16 section
  __hip_bfloat16* xhi    = (__hip_bfloat16*)f32end;
  __hip_bfloat16* xlo    = xhi + (size_t)M * Hh;
  __hip_bfloat16* Wqkvbf = xlo + (size_t)M * Hh;          // 4P x H (q,k,v,gcomb)
  __hip_bfloat16* Wobf   = Wqkvbf + (size_t)4 * Pp * Hh;  // H x P
  __hip_bfloat16* Wcombhi = Wobf + (size_t)Hh * Pp;       // P x H
  __hip_bfloat16* Wcomblo = Wcombhi + (size_t)Pp * Hh;    // P x H
  __hip_bfloat16* end = Wcomblo + (size_t)Pp * Hh;
  __hip_bfloat16* ogbf = xlo;                  // alias: xlo (early) / ogbf (late)
  const bool use_mfma = ws_size >= (size_t)((char*)end - (char*)d_ws);

  const dim3 blk(256);
  if (use_mfma) {
    // ---- conversions & weight preparation ----
    cvt_split<<<(int)((size_t)M * Hh / 2048), blk, 0, stream>>>(x, xhi, xlo, M * Hh);
    cvt_bf16_x4<<<4 * (int)((size_t)Pp * Hh / 2048), blk, 0, stream>>>(
        Wq, Wk, Wv, Wo, Wqkvbf, Wqkvbf + (size_t)Pp * Hh, Wqkvbf + (size_t)2 * Pp * Hh,
        Wobf, Pp * Hh);
    // combined gate weights, exact f32 NN: Wcomb = Wfb@Wfa (hi/lo), Wgcomb = Wgb@Wga (bf16)
    gemm_nn_split<<<dim3(Hh / 64, Pp / 64), blk, 0, stream>>>(Wfb, Wfa, Wcombhi, Wcomblo,
                                                              Pp, Hh, Dd, 0);
    gemm_nn_split<<<dim3(Hh / 64, Pp / 64), blk, 0, stream>>>(Wgb, Wga,
                                                              Wqkvbf + (size_t)3 * Pp * Hh,
                                                              nullptr, Pp, Hh, Dd, 1);
    // ---- main projections (q,k,v,gate fused: N = 4P = 4096 -> 512 blocks) ----
    gemm_bf16_lds<<<dim3(4 * Pp / 128, M / 128), blk, 0, stream>>>(xhi, Wqkvbf, qkvpre, nullptr,
                                                                   M, 4 * Pp, Hh, 0);
    // gf projection with fused softplus/exp epilogue -> gbuf holds eg directly
    gemm_bf16_3t_lds<<<dim3(Pp / 128, M / 64), blk, 0, stream>>>(xhi, xlo, Wcombhi, Wcomblo,
                                                                 gbuf, M, Pp, Hh,
                                                                 dtb, A_log, 1);
    beta_kernel<<<M, 256, 0, stream>>>(x, Wb, betab);
    conv3b_kernel<<<3 * (M / 4) * NHh, 128, 0, stream>>>(qkvpre, cq, ck, cv, qb);
    scan_kernel<<<Bb * NHh * DVQ, 128, 0, stream>>>(qb, kb, vb, gbuf, betab, obuf);
    gated_norm<<<M * NHh, 128, 0, stream>>>(obuf, qkvpre + (size_t)3 * Pp, 4 * Pp, nw, ogbf);
    gemm_bf16_lds<<<dim3(Hh / 128, M / 128), blk, 0, stream>>>(ogbf, Wobf, outp, nullptr,
                                                               M, Hh, Pp, 0);
  } else {
    // f32 fallback
    float* qpre = qkvpre;
    float* kpre = qkvpre + MP;
    float* vpre = qkvpre + 2 * MP;
    float* gate = qkvpre + 3 * MP;
    gemm_nt<<<dim3(Pp / 64, M / 64), blk, 0, stream>>>(x, Wq, qpre, M, Pp, Hh);
    gemm_nt<<<dim3(Pp / 64, M / 64), blk, 0, stream>>>(x, Wk, kpre, M, Pp, Hh);
    gemm_nt<<<dim3(Pp / 64, M / 64), blk, 0, stream>>>(x, Wv, vpre, M, Pp, Hh);
    gemm_nt<<<dim3(Dd / 64, M / 64), blk, 0, stream>>>(x, Wfa, gfa, M, Dd, Hh);
    gemm_nt<<<dim3(Dd / 64, M / 64), blk, 0, stream>>>(x, Wga, gga, M, Dd, Hh);
    gemm_nt<<<dim3(Pp / 64, M / 64), blk, 0, stream>>>(gfa, Wfb, gbuf, M, Pp, Dd);
    gemm_nt<<<dim3(Pp / 64, M / 64), blk, 0, stream>>>(gga, Wgb, gate, M, Pp, Dd);
    beta_kernel<<<M, 256, 0, stream>>>(x, Wb, betab);
    g_kernel<<<(int)(MP / 256), 256, 0, stream>>>(gbuf, dtb, A_log);
    conv_silu_norm<<<M * NHh, 128, 0, stream>>>(qpre, cq, qb, 2, Pp, 0);
    conv_silu_norm<<<M * NHh, 128, 0, stream>>>(kpre, ck, kb, 1, Pp, 0);
    conv_silu_norm<<<M * NHh, 128, 0, stream>>>(vpre, cv, vb, 0, Pp, 0);
    scan_kernel<<<Bb * NHh * DVQ, 128, 0, stream>>>(qb, kb, vb, gbuf, betab, obuf);
    gated_norm<<<M * NHh, 128, 0, stream>>>(obuf, gate, Pp, nw, nullptr);
    gemm_nt<<<dim3(Hh / 64, M / 64), blk, 0, stream>>>(obuf, Wo, outp, M, Hh, Pp);
  }
}

// Round 20
// 411.181 us; speedup vs baseline: 1.1522x; 1.0855x over previous
//
#include <hip/hip_runtime.h>
#include <hip/hip_bf16.h>
#include <cstddef>
#include <cstdint>

#define Bb 2
#define Tt 1024
#define Hh 2048
#define NHh 8
#define Dd 128
#define Pp (NHh * Dd)   // 1024
#define NW (5 * Pp)     // wide GEMM width: q,k,v,gate,gf
#define Kk 4
#define EPSf 1e-6f
#define SCALEf 0.08838834764831845f  // D^-0.5
#define DVQ 16          // dv-splits per (b,h): 16 blocks x 8 columns
#define CHUNK 8         // timesteps per barrier round in scan

typedef short bf16x8 __attribute__((ext_vector_type(8)));
typedef float f32x4 __attribute__((ext_vector_type(4)));
typedef float f32x2 __attribute__((ext_vector_type(2)));   // -> v_pk_*_f32

// DPP rotate-add: 16-lane row sum in 4 VALU ops (all lanes get the sum).
template <int CTRL>
__device__ __forceinline__ float dpp_add(float x) {
  int yi = __builtin_amdgcn_update_dpp(0, __builtin_bit_cast(int, x), CTRL, 0xF, 0xF, true);
  return x + __builtin_bit_cast(float, yi);
}
__device__ __forceinline__ float row16_sum(float x) {
  x = dpp_add<0xB1>(x);
  x = dpp_add<0x4E>(x);
  x = dpp_add<0x124>(x);
  x = dpp_add<0x128>(x);
  return x;
}

// async global->LDS, 16B per lane; lds base must be wave-uniform (HW adds lane*16).
__device__ __forceinline__ void gload_lds16(const void* g, void* l) {
  __builtin_amdgcn_global_load_lds((const __attribute__((address_space(1))) void*)g,
                                   (__attribute__((address_space(3))) void*)l, 16, 0, 0);
}

// ---------------- f32 -> bf16 convert (8 elems/thread) ----------------
__global__ __launch_bounds__(256) void cvt_bf16(const float* __restrict__ src,
                                                __hip_bfloat16* __restrict__ dst, int n) {
  const int i = (blockIdx.x * 256 + threadIdx.x) * 8;
  if (i >= n) return;
  const float4 a = *reinterpret_cast<const float4*>(src + i);
  const float4 b = *reinterpret_cast<const float4*>(src + i + 4);
  __hip_bfloat16 t[8];
  t[0] = __float2bfloat16(a.x); t[1] = __float2bfloat16(a.y);
  t[2] = __float2bfloat16(a.z); t[3] = __float2bfloat16(a.w);
  t[4] = __float2bfloat16(b.x); t[5] = __float2bfloat16(b.y);
  t[6] = __float2bfloat16(b.z); t[7] = __float2bfloat16(b.w);
  *reinterpret_cast<uint4*>(dst + i) = *reinterpret_cast<const uint4*>(t);
}

// ---------------- 4-array f32 -> bf16 (fused weight conversion) ----------------
__global__ __launch_bounds__(256) void cvt_bf16_x4(const float* __restrict__ s0,
                                                   const float* __restrict__ s1,
                                                   const float* __restrict__ s2,
                                                   const float* __restrict__ s3,
                                                   __hip_bfloat16* __restrict__ d0,
                                                   __hip_bfloat16* __restrict__ d1,
                                                   __hip_bfloat16* __restrict__ d2,
                                                   __hip_bfloat16* __restrict__ d3,
                                                   int nper) {
  const int bpa = nper / 2048;
  const int a = blockIdx.x / bpa;
  const int i = (blockIdx.x % bpa) * 2048 + threadIdx.x * 8;
  const float* src = (a == 0) ? s0 : (a == 1) ? s1 : (a == 2) ? s2 : s3;
  __hip_bfloat16* dst = (a == 0) ? d0 : (a == 1) ? d1 : (a == 2) ? d2 : d3;
  const float4 x = *reinterpret_cast<const float4*>(src + i);
  const float4 y = *reinterpret_cast<const float4*>(src + i + 4);
  __hip_bfloat16 t[8];
  t[0] = __float2bfloat16(x.x); t[1] = __float2bfloat16(x.y);
  t[2] = __float2bfloat16(x.z); t[3] = __float2bfloat16(x.w);
  t[4] = __float2bfloat16(y.x); t[5] = __float2bfloat16(y.y);
  t[6] = __float2bfloat16(y.z); t[7] = __float2bfloat16(y.w);
  *reinterpret_cast<uint4*>(dst + i) = *reinterpret_cast<const uint4*>(t);
}

// ---- NN f32 GEMM with bf16 output: C[M,N] = A[M,K] @ B[K,N] ----
// Exact f32 accumulate, bf16 store.
__global__ __launch_bounds__(256) void gemm_nn_bf16(const float* __restrict__ A,
                                                    const float* __restrict__ B,
                                                    __hip_bfloat16* __restrict__ Cbf,
                                                    int M, int N, int K) {
  __shared__ float As[64][33];
  __shared__ float Bs[32][65];
  const int bm = blockIdx.y * 64, bn = blockIdx.x * 64;
  const int tid = threadIdx.x;
  const int tx = tid & 15, ty = tid >> 4;
  float acc[4][4];
#pragma unroll
  for (int i = 0; i < 4; i++)
#pragma unroll
    for (int j = 0; j < 4; j++) acc[i][j] = 0.f;
  for (int k0 = 0; k0 < K; k0 += 32) {
#pragma unroll
    for (int i = 0; i < 8; i++) {
      const int idx = tid + i * 256;            // 0..2047
      const int r = idx >> 5, c = idx & 31;     // A: 64 x 32
      As[r][c] = A[(size_t)(bm + r) * K + k0 + c];
    }
#pragma unroll
    for (int i = 0; i < 8; i++) {
      const int idx = tid + i * 256;
      const int r = idx >> 6, c = idx & 63;     // B: 32 x 64
      Bs[r][c] = B[(size_t)(k0 + r) * N + bn + c];
    }
    __syncthreads();
#pragma unroll
    for (int kk = 0; kk < 32; kk++) {
      float a[4], b[4];
#pragma unroll
      for (int i = 0; i < 4; i++) a[i] = As[ty * 4 + i][kk];
#pragma unroll
      for (int j = 0; j < 4; j++) b[j] = Bs[kk][tx * 4 + j];
#pragma unroll
      for (int i = 0; i < 4; i++)
#pragma unroll
        for (int j = 0; j < 4; j++) acc[i][j] += a[i] * b[j];
    }
    __syncthreads();
  }
#pragma unroll
  for (int i = 0; i < 4; i++) {
    const int row = bm + ty * 4 + i;
#pragma unroll
    for (int j = 0; j < 4; j++) {
      const int col = bn + tx * 4 + j;
      Cbf[(size_t)row * N + col] = __float2bfloat16(acc[i][j]);
    }
  }
}

// ------ bf16 MFMA NT GEMM via global_load_lds (m97 structure): 128x128, BK=64 ------
__global__ __launch_bounds__(256) void gemm_bf16_lds(const __hip_bfloat16* __restrict__ A,
                                                     const __hip_bfloat16* __restrict__ B,
                                                     float* __restrict__ C,
                                                     __hip_bfloat16* __restrict__ Cbf,
                                                     int M, int N, int K, int outmode) {
  __shared__ __align__(16) __hip_bfloat16 As[128 * 64];
  __shared__ __align__(16) __hip_bfloat16 Bs[128 * 64];
  const int tid = threadIdx.x;
  const int wave = tid >> 6;
  const int lane = tid & 63;
  const int wm = (wave >> 1) * 64;
  const int wn = (wave & 1) * 64;
  const int bm = blockIdx.y * 128;
  const int bn = blockIdx.x * 128;
  const int l15 = lane & 15;
  const int l4 = lane >> 4;
  const int srow = lane >> 3;
  const int scol = (lane & 7) * 8;

  f32x4 acc[4][4];
#pragma unroll
  for (int i = 0; i < 4; i++)
#pragma unroll
    for (int j = 0; j < 4; j++) acc[i][j] = (f32x4){0.f, 0.f, 0.f, 0.f};

  for (int k0 = 0; k0 < K; k0 += 64) {
#pragma unroll
    for (int i = 0; i < 4; i++) {
      const int s = wave * 4 + i;
      const int row = s * 8 + srow;
      gload_lds16(A + (size_t)(bm + row) * K + k0 + scol, &As[s * 512]);
      gload_lds16(B + (size_t)(bn + row) * K + k0 + scol, &Bs[s * 512]);
    }
    __syncthreads();
    bf16x8 af[4][2], bfv[4][2];
#pragma unroll
    for (int kf = 0; kf < 2; kf++) {
      const int kc = kf * 32 + l4 * 8;
#pragma unroll
      for (int mf = 0; mf < 4; mf++)
        af[mf][kf] = *reinterpret_cast<const bf16x8*>(&As[(wm + mf * 16 + l15) * 64 + kc]);
#pragma unroll
      for (int nf = 0; nf < 4; nf++)
        bfv[nf][kf] = *reinterpret_cast<const bf16x8*>(&Bs[(wn + nf * 16 + l15) * 64 + kc]);
    }
#pragma unroll
    for (int kf = 0; kf < 2; kf++)
#pragma unroll
      for (int mf = 0; mf < 4; mf++)
#pragma unroll
        for (int nf = 0; nf < 4; nf++)
          acc[mf][nf] = __builtin_amdgcn_mfma_f32_16x16x32_bf16(af[mf][kf], bfv[nf][kf],
                                                                acc[mf][nf], 0, 0, 0);
    __syncthreads();
  }
#pragma unroll
  for (int mf = 0; mf < 4; mf++) {
#pragma unroll
    for (int nf = 0; nf < 4; nf++) {
      const int col = bn + wn + nf * 16 + l15;
#pragma unroll
      for (int r = 0; r < 4; r++) {
        const int row = bm + wm + mf * 16 + l4 * 4 + r;
        if (outmode == 0) C[(size_t)row * N + col] = acc[mf][nf][r];
        else Cbf[(size_t)row * N + col] = __float2bfloat16(acc[mf][nf][r]);
      }
    }
  }
}

// ---------------- generic f32 GEMM (fallback only) ----------------
__global__ __launch_bounds__(256) void gemm_nt(const float* __restrict__ A,
                                               const float* __restrict__ Bm,
                                               float* __restrict__ C,
                                               int M, int N, int Kd) {
  __shared__ float As[16][64];
  __shared__ float Bs[16][64];
  const int bm = blockIdx.y * 64;
  const int bn = blockIdx.x * 64;
  const int tid = threadIdx.x;
  const int tx = tid & 15;
  const int ty = tid >> 4;
  const int lr = tid >> 2;
  const int lc = (tid & 3) << 2;
  float acc[4][4];
#pragma unroll
  for (int i = 0; i < 4; i++)
#pragma unroll
    for (int j = 0; j < 4; j++) acc[i][j] = 0.f;
  for (int k0 = 0; k0 < Kd; k0 += 16) {
    float4 a4 = make_float4(0.f, 0.f, 0.f, 0.f);
    float4 b4 = make_float4(0.f, 0.f, 0.f, 0.f);
    const int ar = bm + lr;
    if (ar < M) a4 = *reinterpret_cast<const float4*>(A + (size_t)ar * Kd + k0 + lc);
    const int br = bn + lr;
    if (br < N) b4 = *reinterpret_cast<const float4*>(Bm + (size_t)br * Kd + k0 + lc);
    As[lc + 0][lr] = a4.x; As[lc + 1][lr] = a4.y; As[lc + 2][lr] = a4.z; As[lc + 3][lr] = a4.w;
    Bs[lc + 0][lr] = b4.x; Bs[lc + 1][lr] = b4.y; Bs[lc + 2][lr] = b4.z; Bs[lc + 3][lr] = b4.w;
    __syncthreads();
#pragma unroll
    for (int kk = 0; kk < 16; kk++) {
      float4 av = *reinterpret_cast<const float4*>(&As[kk][ty << 2]);
      float4 bv = *reinterpret_cast<const float4*>(&Bs[kk][tx << 2]);
      float a[4] = {av.x, av.y, av.z, av.w};
      float b[4] = {bv.x, bv.y, bv.z, bv.w};
#pragma unroll
      for (int i = 0; i < 4; i++)
#pragma unroll
        for (int j = 0; j < 4; j++) acc[i][j] += a[i] * b[j];
    }
    __syncthreads();
  }
#pragma unroll
  for (int i = 0; i < 4; i++) {
    const int row = bm + (ty << 2) + i;
    if (row >= M) continue;
#pragma unroll
    for (int j = 0; j < 4; j++) {
      const int col = bn + (tx << 2) + j;
      if (col < N) C[(size_t)row * N + col] = acc[i][j];
    }
  }
}

// ---------------- beta = sigmoid(x @ Wb^T), Wb (NH,H) ----------------
__global__ __launch_bounds__(256) void beta_kernel(const float* __restrict__ x,
                                                   const float* __restrict__ Wb,
                                                   float* __restrict__ beta) {
  __shared__ float xs[Hh];
  const int m = blockIdx.x;
  const int tid = threadIdx.x;
  for (int i = tid; i < Hh; i += 256) xs[i] = x[(size_t)m * Hh + i];
  __syncthreads();
  const int h = tid >> 5;
  const int lane = tid & 31;
  float acc = 0.f;
  for (int i = lane; i < Hh; i += 32) acc += xs[i] * Wb[(size_t)h * Hh + i];
#pragma unroll
  for (int o = 16; o > 0; o >>= 1) acc += __shfl_down(acc, o, 32);
  if (lane == 0) beta[(size_t)m * NHh + h] = 1.f / (1.f + expf(-acc));
}

// -- eg = exp(-exp(A_log[h]) * softplus(gf + dt_bias)); strided src -> dense dst --
__global__ __launch_bounds__(256) void g_kernel(const float* __restrict__ src,
                                                int sstride, int scol,
                                                float* __restrict__ dst,
                                                const float* __restrict__ dtb,
                                                const float* __restrict__ A_log) {
  const size_t i = (size_t)blockIdx.x * 256 + threadIdx.x;
  const int c = (int)(i % Pp);
  const size_t row = i / Pp;
  const int h = c / Dd;
  const float xv = src[row * sstride + scol + c] + dtb[c];
  const float sp = (xv > 20.f) ? xv : log1pf(expf(xv));
  dst[i] = expf(-expf(A_log[h]) * sp);
}

// ------- depthwise causal conv(K=4) + SiLU (+ optional l2norm) (fallback) -------
__global__ __launch_bounds__(128) void conv_silu_norm(const float* __restrict__ xin,
                                                      const float* __restrict__ w,
                                                      float* __restrict__ out,
                                                      int mode, int instride, int coff) {
  const int idx = blockIdx.x;            // (b*T + t)*NH + h
  const int h = idx % NHh;
  const int bt = idx / NHh;
  const int t = bt % Tt;
  const int d = threadIdx.x;
  const int c = h * Dd + d;
  float acc = 0.f;
#pragma unroll
  for (int j = 0; j < Kk; j++) {
    const int tt = t - (Kk - 1) + j;
    float xv = 0.f;
    if (tt >= 0) xv = xin[(size_t)(bt - (Kk - 1) + j) * instride + coff + c];
    acc += w[c * Kk + j] * xv;
  }
  float y = acc / (1.f + expf(-acc));    // silu
  float r = y;
  if (mode > 0) {
    float ss = y * y;
#pragma unroll
    for (int o = 32; o > 0; o >>= 1) ss += __shfl_down(ss, o);
    __shared__ float red[2];
    if ((d & 63) == 0) red[d >> 6] = ss;
    __syncthreads();
    const float tot = red[0] + red[1];
    const float inv = rsqrtf(tot + EPSf);
    r = y * inv * (mode == 2 ? SCALEf : 1.f);
  }
  out[(size_t)bt * Pp + c] = r;
}

// ------- all three convs, 4 timesteps per block: grid = 3 * (M/4) * NH -------
__global__ __launch_bounds__(128) void conv3b_kernel(const float* __restrict__ qkvpre,
                                                     const float* __restrict__ cq,
                                                     const float* __restrict__ ck,
                                                     const float* __restrict__ cv,
                                                     float* __restrict__ outbase,
                                                     int instride) {
  const int nper = (Bb * Tt / 4) * NHh;   // 4096
  const int which = blockIdx.x / nper;    // 0:q 1:k 2:v
  const int idx = blockIdx.x % nper;
  const float* w = (which == 0) ? cq : (which == 1) ? ck : cv;
  const int mode = (which == 0) ? 2 : (which == 1) ? 1 : 0;
  const int h = idx % NHh;
  const int bt0 = (idx / NHh) * 4;        // 4-aligned, never crosses batch
  const int t0 = bt0 % Tt;
  const int d = threadIdx.x;
  const int c = h * Dd + d;

  float xw[7];
#pragma unroll
  for (int i = 0; i < 7; i++) {
    const int tt = t0 - 3 + i;
    xw[i] = (tt >= 0) ? qkvpre[(size_t)(bt0 - 3 + i) * instride + which * Pp + c] : 0.f;
  }
  const float w0 = w[c * Kk + 0], w1 = w[c * Kk + 1], w2 = w[c * Kk + 2], w3 = w[c * Kk + 3];
  float y[4];
#pragma unroll
  for (int jj = 0; jj < 4; jj++) {
    const float a = w0 * xw[jj] + w1 * xw[jj + 1] + w2 * xw[jj + 2] + w3 * xw[jj + 3];
    y[jj] = a / (1.f + expf(-a));   // silu
  }
  if (mode > 0) {
    float ss[4];
#pragma unroll
    for (int jj = 0; jj < 4; jj++) ss[jj] = y[jj] * y[jj];
#pragma unroll
    for (int o = 32; o > 0; o >>= 1) {
#pragma unroll
      for (int jj = 0; jj < 4; jj++) ss[jj] += __shfl_down(ss[jj], o);
    }
    __shared__ float red[2][4];
    if ((d & 63) == 0) {
#pragma unroll
      for (int jj = 0; jj < 4; jj++) red[d >> 6][jj] = ss[jj];
    }
    __syncthreads();
    const float sc = (mode == 2) ? SCALEf : 1.f;
#pragma unroll
    for (int jj = 0; jj < 4; jj++)
      y[jj] = y[jj] * rsqrtf(red[0][jj] + red[1][jj] + EPSf) * sc;
  }
  float* outp = outbase + (size_t)which * (Bb * Tt) * Pp;
#pragma unroll
  for (int jj = 0; jj < 4; jj++) outp[(size_t)(bt0 + jj) * Pp + c] = y[jj];
}

// ---- gated delta-rule scan (r11-proven): packed-f32 math, double-buffered LDS,
// ---- 1-step reg pipeline, kt=k*e off-chain, s = pk_fma(k, delta, e*s).
__global__ __launch_bounds__(128) void scan_kernel(const float* __restrict__ q,
                                                   const float* __restrict__ k,
                                                   const float* __restrict__ v,
                                                   const float* __restrict__ eg,
                                                   const float* __restrict__ beta,
                                                   float* __restrict__ o) {
  const int blk = blockIdx.x;
  const int bh = blk & 15;
  const int dvq = blk >> 4;        // 0..15
  const int b = bh >> 3, h = bh & 7;
  const int tid = threadIdx.x;
  const int qr = tid & 15;
  const int dvl = tid >> 4;        // 0..7
  const int dv = dvq * 8 + dvl;

  __shared__ __align__(16) float qs[2][CHUNK][16][12];
  __shared__ __align__(16) float ks[2][CHUNK][16][12];
  __shared__ __align__(16) float legs[2][CHUNK][16][12];
  __shared__ float vs[2][CHUNK][8];
  __shared__ float betas[2][CHUNK];

  f32x2 s2[4];
#pragma unroll
  for (int i = 0; i < 4; i++) s2[i] = (f32x2){0.f, 0.f};

  const size_t base = (size_t)(b * Tt) * Pp + h * Dd;
  const int le = tid;

  float rq[CHUNK], rk[CHUNK], re[CHUNK], rv[CHUNK], rb = 0.f;
  auto load_chunk = [&](int t0) {
    const size_t coff = base + (size_t)t0 * Pp;
#pragma unroll
    for (int j = 0; j < CHUNK; j++) {
      rq[j] = q[coff + (size_t)j * Pp + le];
      rk[j] = k[coff + (size_t)j * Pp + le];
      re[j] = eg[coff + (size_t)j * Pp + le];
    }
    if (tid < 8) {
#pragma unroll
      for (int j = 0; j < CHUNK; j++) rv[j] = v[coff + (size_t)j * Pp + dvq * 8 + tid];
    } else if (tid < 8 + CHUNK) {
      rb = beta[(size_t)(b * Tt + t0 + tid - 8) * NHh + h];
    }
  };
  auto write_lds = [&](int bufw) {
#pragma unroll
    for (int j = 0; j < CHUNK; j++) {
      qs[bufw][j][le >> 3][le & 7] = rq[j];
      ks[bufw][j][le >> 3][le & 7] = rk[j];
      legs[bufw][j][le >> 3][le & 7] = re[j];
    }
    if (tid < 8) {
#pragma unroll
      for (int j = 0; j < CHUNK; j++) vs[bufw][j][tid] = rv[j];
    } else if (tid < 8 + CHUNK) {
      betas[bufw][tid - 8] = rb;
    }
  };
  auto unpack = [](const float4& a, const float4& b, f32x2 out[4]) {
    out[0] = (f32x2){a.x, a.y}; out[1] = (f32x2){a.z, a.w};
    out[2] = (f32x2){b.x, b.y}; out[3] = (f32x2){b.z, b.w};
  };

  load_chunk(0);
  write_lds(0);
  __syncthreads();
  const int NC = Tt / CHUNK;
  size_t off = base;
  for (int c = 0; c < NC; c++) {
    if (c + 1 < NC) load_chunk((c + 1) * CHUNK);  // global latency hides under compute
    const int buf = c & 1;
    float vv[CHUNK], bb[CHUNK], opart[CHUNK];
#pragma unroll
    for (int j = 0; j < CHUNK; j++) { vv[j] = vs[buf][j][dvl]; bb[j] = betas[buf][j]; }

    f32x2 ck2[4], ce2[4], cq2[4], kt2[4];
    {
      const float4 k0 = *reinterpret_cast<const float4*>(&ks[buf][0][qr][0]);
      const float4 k1 = *reinterpret_cast<const float4*>(&ks[buf][0][qr][4]);
      const float4 e0 = *reinterpret_cast<const float4*>(&legs[buf][0][qr][0]);
      const float4 e1 = *reinterpret_cast<const float4*>(&legs[buf][0][qr][4]);
      const float4 q0 = *reinterpret_cast<const float4*>(&qs[buf][0][qr][0]);
      const float4 q1 = *reinterpret_cast<const float4*>(&qs[buf][0][qr][4]);
      unpack(k0, k1, ck2); unpack(e0, e1, ce2); unpack(q0, q1, cq2);
#pragma unroll
      for (int i = 0; i < 4; i++) kt2[i] = ck2[i] * ce2[i];
    }

#pragma unroll
    for (int j = 0; j < CHUNK; j++) {
      float4 nk0, nk1, ne0, ne1, nq0, nq1;
      if (j + 1 < CHUNK) {                    // prefetch next step's LDS reads
        nk0 = *reinterpret_cast<const float4*>(&ks[buf][j + 1][qr][0]);
        nk1 = *reinterpret_cast<const float4*>(&ks[buf][j + 1][qr][4]);
        ne0 = *reinterpret_cast<const float4*>(&legs[buf][j + 1][qr][0]);
        ne1 = *reinterpret_cast<const float4*>(&legs[buf][j + 1][qr][4]);
        nq0 = *reinterpret_cast<const float4*>(&qs[buf][j + 1][qr][0]);
        nq1 = *reinterpret_cast<const float4*>(&qs[buf][j + 1][qr][4]);
      }
      // decayed state (off the kv chain)
      f32x2 es0 = ce2[0] * s2[0], es1 = ce2[1] * s2[1];
      f32x2 es2v = ce2[2] * s2[2], es3 = ce2[3] * s2[3];
      // kv partials: 2 packed chains
      f32x2 kva = kt2[0] * s2[0];
      f32x2 kvb = kt2[1] * s2[1];
      kva = kt2[2] * s2[2] + kva;
      kvb = kt2[3] * s2[3] + kvb;
      kva = kva + kvb;
      const float kvp = row16_sum(kva.x + kva.y);
      const float delta = (vv[j] - kvp) * bb[j];
      const f32x2 d2 = (f32x2){delta, delta};
      f32x2 o2;
      s2[0] = ck2[0] * d2 + es0;  o2 = cq2[0] * s2[0];
      s2[1] = ck2[1] * d2 + es1;  o2 = cq2[1] * s2[1] + o2;
      s2[2] = ck2[2] * d2 + es2v; o2 = cq2[2] * s2[2] + o2;
      s2[3] = ck2[3] * d2 + es3;  o2 = cq2[3] * s2[3] + o2;
      opart[j] = o2.x + o2.y;                 // reduction deferred
      if (j + 1 < CHUNK) {
        unpack(nk0, nk1, ck2); unpack(ne0, ne1, ce2); unpack(nq0, nq1, cq2);
#pragma unroll
        for (int i = 0; i < 4; i++) kt2[i] = ck2[i] * ce2[i];
      }
    }
#pragma unroll
    for (int j = 0; j < CHUNK; j++) opart[j] = row16_sum(opart[j]);
    if (qr == 0) {
#pragma unroll
      for (int j = 0; j < CHUNK; j++) o[off + (size_t)j * Pp + dv] = opart[j];
    }
    if (c + 1 < NC) write_lds(buf ^ 1);       // other buffer: no pre-barrier needed
    __syncthreads();
    off += (size_t)CHUNK * Pp;
  }
}

// ------- og = o * sigmoid(gate); rms-norm over D; * norm_weight -------
__global__ __launch_bounds__(128) void gated_norm(float* __restrict__ o,
                                                  const float* __restrict__ gate,
                                                  int gstride,
                                                  const float* __restrict__ nw,
                                                  __hip_bfloat16* __restrict__ ogbf) {
  const int idx = blockIdx.x;
  const int h = idx % NHh;
  const int bt = idx / NHh;
  const int d = threadIdx.x;
  const size_t off = (size_t)bt * Pp + h * Dd;
  const float ov = o[off + d];
  const float gt = gate[(size_t)bt * gstride + h * Dd + d];
  const float val = ov / (1.f + expf(-gt));
  float ss = val * val;
#pragma unroll
  for (int sh = 32; sh > 0; sh >>= 1) ss += __shfl_down(ss, sh);
  __shared__ float red[2];
  if ((d & 63) == 0) red[d >> 6] = ss;
  __syncthreads();
  const float mean = (red[0] + red[1]) * (1.f / Dd);
  const float res = val * rsqrtf(mean + EPSf) * nw[d];
  if (ogbf != nullptr) ogbf[off + d] = __float2bfloat16(res);
  else o[off + d] = res;
}

extern "C" void kernel_launch(void* const* d_in, const int* in_sizes, int n_in,
                              void* d_out, int out_size, void* d_ws, size_t ws_size,
                              hipStream_t stream) {
  const float* x     = (const float*)d_in[0];
  const float* Wq    = (const float*)d_in[1];
  const float* Wk    = (const float*)d_in[2];
  const float* Wv    = (const float*)d_in[3];
  const float* cq    = (const float*)d_in[4];
  const float* ck    = (const float*)d_in[5];
  const float* cv    = (const float*)d_in[6];
  const float* A_log = (const float*)d_in[7];
  const float* dtb   = (const float*)d_in[8];
  const float* Wfa   = (const float*)d_in[9];
  const float* Wfb   = (const float*)d_in[10];
  const float* Wb    = (const float*)d_in[11];
  const float* Wga   = (const float*)d_in[12];
  const float* Wgb   = (const float*)d_in[13];
  const float* nw    = (const float*)d_in[14];
  const float* Wo    = (const float*)d_in[15];
  float* outp = (float*)d_out;

  const int M = Bb * Tt;          // 2048
  const size_t MP = (size_t)M * Pp;
  float* ws = (float*)d_ws;
  // f32 section
  float* qkvpre = ws;                          // M x NW (q,k,v,gate,gf)
  float* qb   = qkvpre + (size_t)M * NW;
  float* kb   = qb + MP;
  float* vb   = kb + MP;
  float* gbuf = vb + MP;
  float* obuf = gbuf + MP;
  float* betab = obuf + MP;                    // M*NH
  float* gfa  = betab + (size_t)M * NHh;       // M*D (fallback)
  float* gga  = gfa + (size_t)M * Dd;          // M*D (fallback)
  float* f32end = gga + (size_t)M * Dd;

  // bf16 section
  __hip_bfloat16* xhi    = (__hip_bfloat16*)f32end;
  __hip_bfloat16* Wqkvbf = xhi + (size_t)M * Hh;          // NW x H (q,k,v,gcomb,comb)
  __hip_bfloat16* Wobf   = Wqkvbf + (size_t)NW * Hh;      // H x P
  __hip_bfloat16* end    = Wobf + (size_t)Hh * Pp;
  __hip_bfloat16* ogbf   = (__hip_bfloat16*)qb;           // alias: qb dead after scan
  const bool use_mfma = ws_size >= (size_t)((char*)end - (char*)d_ws);

  const dim3 blk(256);
  if (use_mfma) {
    // ---- conversions & weight preparation ----
    cvt_bf16<<<(int)((size_t)M * Hh / 2048), blk, 0, stream>>>(x, xhi, M * Hh);
    cvt_bf16_x4<<<4 * (int)((size_t)Pp * Hh / 2048), blk, 0, stream>>>(
        Wq, Wk, Wv, Wo, Wqkvbf, Wqkvbf + (size_t)Pp * Hh, Wqkvbf + (size_t)2 * Pp * Hh,
        Wobf, Pp * Hh);
    // combined gate weights, exact f32 NN -> bf16: Wgcomb = Wgb@Wga, Wcomb = Wfb@Wfa
    gemm_nn_bf16<<<dim3(Hh / 64, Pp / 64), blk, 0, stream>>>(Wgb, Wga,
                                                             Wqkvbf + (size_t)3 * Pp * Hh,
                                                             Pp, Hh, Dd);
    gemm_nn_bf16<<<dim3(Hh / 64, Pp / 64), blk, 0, stream>>>(Wfb, Wfa,
                                                             Wqkvbf + (size_t)4 * Pp * Hh,
                                                             Pp, Hh, Dd);
    // ---- main projections (q,k,v,gate,gf fused: N = 5P = 5120 -> 640 blocks) ----
    gemm_bf16_lds<<<dim3(NW / 128, M / 128), blk, 0, stream>>>(xhi, Wqkvbf, qkvpre, nullptr,
                                                               M, NW, Hh, 0);
    // eg = exp(-exp(A_log)*softplus(gf+dtb)): strided gf (col 4P) -> dense gbuf
    g_kernel<<<(int)(MP / 256), blk, 0, stream>>>(qkvpre, NW, 4 * Pp, gbuf, dtb, A_log);
    beta_kernel<<<M, 256, 0, stream>>>(x, Wb, betab);
    conv3b_kernel<<<3 * (M / 4) * NHh, 128, 0, stream>>>(qkvpre, cq, ck, cv, qb, NW);
    scan_kernel<<<Bb * NHh * DVQ, 128, 0, stream>>>(qb, kb, vb, gbuf, betab, obuf);
    gated_norm<<<M * NHh, 128, 0, stream>>>(obuf, qkvpre + (size_t)3 * Pp, NW, nw, ogbf);
    gemm_bf16_lds<<<dim3(Hh / 128, M / 128), blk, 0, stream>>>(ogbf, Wobf, outp, nullptr,
                                                               M, Hh, Pp, 0);
  } else {
    // f32 fallback
    float* qpre = qkvpre;
    float* kpre = qkvpre + MP;
    float* vpre = qkvpre + 2 * MP;
    float* gate = qkvpre + 3 * MP;
    gemm_nt<<<dim3(Pp / 64, M / 64), blk, 0, stream>>>(x, Wq, qpre, M, Pp, Hh);
    gemm_nt<<<dim3(Pp / 64, M / 64), blk, 0, stream>>>(x, Wk, kpre, M, Pp, Hh);
    gemm_nt<<<dim3(Pp / 64, M / 64), blk, 0, stream>>>(x, Wv, vpre, M, Pp, Hh);
    gemm_nt<<<dim3(Dd / 64, M / 64), blk, 0, stream>>>(x, Wfa, gfa, M, Dd, Hh);
    gemm_nt<<<dim3(Dd / 64, M / 64), blk, 0, stream>>>(x, Wga, gga, M, Dd, Hh);
    gemm_nt<<<dim3(Pp / 64, M / 64), blk, 0, stream>>>(gfa, Wfb, gbuf, M, Pp, Dd);
    gemm_nt<<<dim3(Pp / 64, M / 64), blk, 0, stream>>>(gga, Wgb, gate, M, Pp, Dd);
    beta_kernel<<<M, 256, 0, stream>>>(x, Wb, betab);
    g_kernel<<<(int)(MP / 256), blk, 0, stream>>>(gbuf, Pp, 0, gbuf, dtb, A_log);
    conv_silu_norm<<<M * NHh, 128, 0, stream>>>(qpre, cq, qb, 2, Pp, 0);
    conv_silu_norm<<<M * NHh, 128, 0, stream>>>(kpre, ck, kb, 1, Pp, 0);
    conv_silu_norm<<<M * NHh, 128, 0, stream>>>(vpre, cv, vb, 0, Pp, 0);
    scan_kernel<<<Bb * NHh * DVQ, 128, 0, stream>>>(qb, kb, vb, gbuf, betab, obuf);
    gated_norm<<<M * NHh, 128, 0, stream>>>(obuf, gate, Pp, nw, nullptr);
    gemm_nt<<<dim3(Hh / 64, M / 64), blk, 0, stream>>>(obuf, Wo, outp, M, Hh, Pp);
  }
}